// Round 19
// baseline (609.115 us; speedup 1.0000x reference)
//
#include <hip/hip_runtime.h>
#include <hip/hip_bf16.h>
#include <math.h>

#define BB 4
#define NN 2048
#define KK 32
#define GG 2
constexpr int BNr = BB * NN;       // 8192 point-rows per group
constexpr int SGr = BB * NN * KK;  // 262144 sample rows per group
constexpr int SR  = GG * SGr;      // 524288 total sample rows

typedef __hip_bfloat16 bf16;
typedef __attribute__((ext_vector_type(8))) short bf16x8;
typedef __attribute__((ext_vector_type(4))) short s16x4;
typedef __attribute__((ext_vector_type(4))) float f32x4;
__device__ __forceinline__ float b2f(bf16 v) { return __bfloat162float(v); }
__device__ __forceinline__ bf16  f2b(float v) { return __float2bfloat16(v); }
__device__ __forceinline__ short f2bs(float v) { bf16 b = f2b(v); return *(short*)&b; }
__device__ __forceinline__ float bs2f(short s) { bf16 b; *(short*)&b = s; return b2f(b); }

// XOR swizzles for LDS tiles (byte-offset based; row = stride 128B / 256B)
#define SWZ128(b) ((b) ^ ((((b) >> 7) & 7) << 4))
#define SWZ256(b) ((b) ^ ((((b) >> 8) & 7) << 4))

// ------------------------------------------------- kNN (wave-per-query) ---
// + fused layer-1 feature Gram -> per-block partials (no global atomics).
__global__ __launch_bounds__(256) void knn_kernel(const float* __restrict__ src,
                                                  const float* __restrict__ tgt,
                                                  int* __restrict__ idx_out,
                                                  float* __restrict__ g1part) {
    __shared__ float pts[3 * NN];   // 24 KB
    __shared__ float xxs[NN];       // 8 KB
    __shared__ int   sel[4][32];
    __shared__ float Gs[27];
    int blk = blockIdx.x;           // (g*B+b)*(NN/4) + chunk
    int gb = blk >> 9;              // / (NN/4)
    int chunk = blk & 511;
    int g = gb >> 2, b = gb & 3;
    const float* x = (g == 0 ? src : tgt) + (size_t)b * 3 * NN;
    int t = threadIdx.x;
    if (t < 27) Gs[t] = 0.f;
    for (int i = t; i < 3 * NN; i += 256) pts[i] = x[i];
    __syncthreads();
    for (int m = t; m < NN; m += 256) {
        float p0 = pts[m], p1 = pts[NN + m], p2 = pts[2 * NN + m];
        xxs[m] = p0 * p0 + p1 * p1 + p2 * p2;
    }
    __syncthreads();
    int w = t >> 6, l = t & 63;
    int n = chunk * 4 + w;
    float q0 = pts[n], q1 = pts[NN + n], q2 = pts[2 * NN + n];
    float xxn = xxs[n];
    float d2[32];
#pragma unroll
    for (int s = 0; s < 32; ++s) {
        int m = s * 64 + l;
        float dot = q0 * pts[m] + q1 * pts[NN + m] + q2 * pts[2 * NN + m];
        d2[s] = (xxn - 2.0f * dot) + xxs[m];
    }
    // cached group minima (4 groups x 8 slots)
    float gval[4]; int gslot[4];
#pragma unroll
    for (int G = 0; G < 4; ++G) {
        float v = d2[G * 8]; int sl = G * 8;
#pragma unroll
        for (int s = 1; s < 8; ++s)
            if (d2[G * 8 + s] < v) { v = d2[G * 8 + s]; sl = G * 8 + s; }
        gval[G] = v; gslot[G] = sl;
    }
    int* outp = idx_out + ((size_t)gb * NN + n) * KK;
    for (int k = 0; k < KK; ++k) {
        float bv = fminf(fminf(gval[0], gval[1]), fminf(gval[2], gval[3]));
        float gv = bv;
#pragma unroll
        for (int off = 1; off < 64; off <<= 1) gv = fminf(gv, __shfl_xor(gv, off));
        unsigned long long mask = __ballot(bv == gv);
        int winner = (int)__builtin_ctzll(mask);
        if (l == winner) {
            int grp = (gval[0] == gv) ? 0 : (gval[1] == gv) ? 1 : (gval[2] == gv) ? 2 : 3;
#pragma unroll
            for (int G = 0; G < 4; ++G)
                if (G == grp) {
                    int bs = gslot[G];
                    outp[k] = bs * 64 + l;
                    sel[w][k] = bs * 64 + l;
#pragma unroll
                    for (int s = 0; s < 8; ++s)
                        if (G * 8 + s == bs) d2[G * 8 + s] = INFINITY;
                    float v = d2[G * 8]; int sl = G * 8;
#pragma unroll
                    for (int s = 1; s < 8; ++s)
                        if (d2[G * 8 + s] < v) { v = d2[G * 8 + s]; sl = G * 8 + s; }
                    gval[G] = v; gslot[G] = sl;
                }
        }
    }
    __syncthreads();   // sel visible across lanes
    // feature Gram accumulation (layer-1 BN stats)
    float nx = 0.f, ny = 0.f, nz = 0.f;
    if (l < 32) {
        int m = sel[w][l];
        nx = pts[m]; ny = pts[NN + m]; nz = pts[2 * NN + m];
    }
    float v9[9] = {nx * nx, nx * ny, nx * nz, ny * ny, ny * nz, nz * nz, nx, ny, nz};
#pragma unroll
    for (int e = 0; e < 9; ++e) {
#pragma unroll
        for (int off = 1; off < 64; off <<= 1) v9[e] += __shfl_xor(v9[e], off);
    }
    if (l == 0) {
        float c3[3] = {q0, q1, q2};
#pragma unroll
        for (int e = 0; e < 6; ++e) atomicAdd(&Gs[e], v9[e]);
#pragma unroll
        for (int a = 0; a < 3; ++a)
#pragma unroll
            for (int bb = 0; bb < 3; ++bb)
                atomicAdd(&Gs[6 + a * 3 + bb], v9[6 + a] * c3[bb]);
        atomicAdd(&Gs[15], 32.f * q0 * q0);
        atomicAdd(&Gs[16], 32.f * q0 * q1);
        atomicAdd(&Gs[17], 32.f * q0 * q2);
        atomicAdd(&Gs[18], 32.f * q1 * q1);
        atomicAdd(&Gs[19], 32.f * q1 * q2);
        atomicAdd(&Gs[20], 32.f * q2 * q2);
        atomicAdd(&Gs[21], v9[6]);
        atomicAdd(&Gs[22], v9[7]);
        atomicAdd(&Gs[23], v9[8]);
        atomicAdd(&Gs[24], 32.f * q0);
        atomicAdd(&Gs[25], 32.f * q1);
        atomicAdd(&Gs[26], 32.f * q2);
    }
    __syncthreads();
    if (t < 27) g1part[(size_t)blk * 32 + t] = Gs[t];   // plain store, no atomics
}

// reduce per-block Gram partials: 54 blocks, one (g,e) each
__global__ __launch_bounds__(256) void reduce_g1_kernel(const float* __restrict__ part,
                                                        float* __restrict__ g1s) {
    __shared__ float red[256];
    int bx = blockIdx.x;
    int g = bx / 27, e = bx - g * 27;
    int t = threadIdx.x;
    float s = 0.f;
    for (int b = t; b < 2048; b += 256) s += part[((size_t)g * 2048 + b) * 32 + e];
    red[t] = s; __syncthreads();
    for (int st = 128; st > 0; st >>= 1) { if (t < st) red[t] += red[t + st]; __syncthreads(); }
    if (t == 0) g1s[g * 27 + e] = red[0];
}

// ---------------------------------------------------------------- misc ----
__global__ void zero_kernel(float* __restrict__ p, int n) {
    int i = blockIdx.x * 256 + threadIdx.x;
    if (i < n) p[i] = 0.f;
}

__global__ void cvt_all_kernel(const float* __restrict__ w2, const float* __restrict__ w3,
                               const float* __restrict__ w4, const float* __restrict__ w5,
                               bf16* __restrict__ w2b, bf16* __restrict__ w3b,
                               bf16* __restrict__ w4b, bf16* __restrict__ w5b) {
    int i = blockIdx.x * 256 + threadIdx.x;
    if (i < 4096)   w2b[i] = f2b(w2[i]);
    if (i < 8192)   w3b[i] = f2b(w3[i]);
    if (i < 32768)  w4b[i] = f2b(w4[i]);
    if (i < 262144) w5b[i] = f2b(w5[i]);
}

// finalize: compute scale/shift and zero the consumed sums for the next stage
__global__ void finalize_bn_kernel(float* __restrict__ sums, int C,
                                   const float* __restrict__ gamma,
                                   const float* __restrict__ beta,
                                   float cnt, float* __restrict__ params) {
    int i = blockIdx.x * blockDim.x + threadIdx.x;
    if (i >= GG * C) return;
    int g = i / C, c = i - g * C;
    float s  = sums[(g * 512 + c) * 2 + 0];
    float sq = sums[(g * 512 + c) * 2 + 1];
    float mean = s / cnt;
    float var = sq / cnt - mean * mean;
    if (var < 0.f) var = 0.f;
    float sc = gamma[c] * rsqrtf(var + 1e-5f);
    params[(g * 512 + c) * 2 + 0] = sc;
    params[(g * 512 + c) * 2 + 1] = beta[c] - mean * sc;
    sums[(g * 512 + c) * 2 + 0] = 0.f;
    sums[(g * 512 + c) * 2 + 1] = 0.f;
}

// layer-1 BN params from feature Gram: s = w.fsum, q = w^T G w
__global__ void finalize_l1_kernel(const float* __restrict__ g1s,
                                   const float* __restrict__ w1,
                                   const float* __restrict__ gamma,
                                   const float* __restrict__ beta,
                                   float cnt, float* __restrict__ params) {
    int i = blockIdx.x * blockDim.x + threadIdx.x;
    if (i >= GG * 64) return;
    int g = i >> 6, o = i & 63;
    const float* G = g1s + g * 27;
    float wv[6];
#pragma unroll
    for (int c = 0; c < 6; ++c) wv[c] = w1[o * 6 + c];
    float s = wv[0] * G[21] + wv[1] * G[22] + wv[2] * G[23] +
              wv[3] * G[24] + wv[4] * G[25] + wv[5] * G[26];
    const int UT[6][6] = {{0, 1, 2, 6, 7, 8},   {1, 3, 4, 9, 10, 11},
                          {2, 4, 5, 12, 13, 14},{6, 9, 12, 15, 16, 17},
                          {7, 10, 13, 16, 18, 19},{8, 11, 14, 17, 19, 20}};
    float q = 0.f;
#pragma unroll
    for (int a = 0; a < 6; ++a)
#pragma unroll
        for (int bb = 0; bb < 6; ++bb) q += wv[a] * wv[bb] * G[UT[a][bb]];
    float mean = s / cnt;
    float var = q / cnt - mean * mean;
    if (var < 0.f) var = 0.f;
    float sc = gamma[o] * rsqrtf(var + 1e-5f);
    params[(g * 512 + o) * 2 + 0] = sc;
    params[(g * 512 + o) * 2 + 1] = beta[o] - mean * sc;
}

// ----------------------------------------------- MFMA layers 1+2 ----------
// Apply pass only: gather -> l1 MFMA -> bn1+relu -> F1 (LDS) + x1 -> cat,
// l2 MFMA -> store RAW h2pre -> H2, accumulate h2pre stats -> sums.
__global__ __launch_bounds__(256, 3) void l12_mfma(
    const float* __restrict__ src, const float* __restrict__ tgt,
    const float* __restrict__ w1, const bf16* __restrict__ w2b,
    const int* __restrict__ idx, const float* __restrict__ p1,
    bf16* __restrict__ H2, bf16* __restrict__ cat, float* __restrict__ sums) {
    __shared__ char F1s[32768];    // [256][64] bf16 swz128
    __shared__ char W2s[8192];     // [64][64] bf16 swz128
    __shared__ float epiA[512];    // x1 int-max [8][64]
    __shared__ float epiB[128];    // h2 stats [64][2]
    int tid = threadIdx.x;
    int w = tid >> 6, l = tid & 63, lg = l >> 4, lr = l & 15;
    long long row0 = (long long)blockIdx.x * 256;
    int g = (int)(row0 / SGr);

    epiA[tid] = 0.f; epiA[tid + 256] = 0.f;
    if (tid < 128) epiB[tid] = 0.f;
    for (int s = tid; s < 512; s += 256)
        *(bf16x8*)(W2s + SWZ128(s * 16)) = *(const bf16x8*)(w2b + s * 8);

    bf16x8 af[4];
#pragma unroll
    for (int i = 0; i < 4; ++i) {
        af[i] = (bf16x8){0, 0, 0, 0, 0, 0, 0, 0};
        if (lg == 0) {
            int rr = (int)row0 + w * 64 + 16 * i + lr;
            int nrow = rr >> 5;
            int n = nrow & (NN - 1);
            int gb = nrow >> 11;
            int b = gb & 3, gg = gb >> 2;
            const float* x = (gg ? tgt : src) + (size_t)b * 3 * NN;
            int j = idx[rr];
            af[i][0] = f2bs(x[j]);
            af[i][1] = f2bs(x[NN + j]);
            af[i][2] = f2bs(x[2 * NN + j]);
            af[i][3] = f2bs(x[n]);
            af[i][4] = f2bs(x[NN + n]);
            af[i][5] = f2bs(x[2 * NN + n]);
        }
    }
    bf16x8 bf1[4];
#pragma unroll
    for (int j = 0; j < 4; ++j) {
        bf1[j] = (bf16x8){0, 0, 0, 0, 0, 0, 0, 0};
        if (lg == 0) {
            int o = 16 * j + lr;
#pragma unroll
            for (int c = 0; c < 6; ++c) bf1[j][c] = f2bs(w1[o * 6 + c]);
        }
    }

    f32x4 acc1[4][4] = {};
#pragma unroll
    for (int i = 0; i < 4; ++i)
#pragma unroll
        for (int j = 0; j < 4; ++j)
            acc1[i][j] = __builtin_amdgcn_mfma_f32_16x16x32_bf16(af[i], bf1[j], acc1[i][j], 0, 0, 0);

    __syncthreads();

    // bn1 + relu -> F1 (bf16) + x1 max
#pragma unroll
    for (int j = 0; j < 4; ++j) {
        int c = 16 * j + lr;
        float sc = p1[(g * 512 + c) * 2], sh = p1[(g * 512 + c) * 2 + 1];
#pragma unroll
        for (int i = 0; i < 4; ++i) {
            float m = 0.f;
#pragma unroll
            for (int r = 0; r < 4; ++r) {
                float v = fmaf(acc1[i][j][r], sc, sh);
                v = v > 0.f ? v : 0.f;
                m = fmaxf(m, v);
                int rowi = w * 64 + 16 * i + 4 * lg + r;
                *(bf16*)(F1s + SWZ128((rowi * 64 + c) * 2)) = f2b(v);
            }
            int p = 2 * w + (i >> 1);
            atomicMax((int*)epiA + p * 64 + c, __float_as_int(m));
        }
    }
    __syncthreads();

    {
        long long pt0 = row0 >> 5;
        for (int e = tid; e < 512; e += 256) {
            int p = e >> 6, c = e & 63;
            cat[(pt0 + p) * 512 + c] = f2b(__int_as_float(((int*)epiA)[p * 64 + c]));
        }
    }

    // layer 2 MFMA: F1 @ w2^T
    f32x4 acc2[4][4] = {};
#pragma unroll
    for (int ks = 0; ks < 2; ++ks) {
        bf16x8 bv[4];
#pragma unroll
        for (int j = 0; j < 4; ++j)
            bv[j] = *(bf16x8*)(W2s + SWZ128(((16 * j + lr) * 64 + ks * 32 + lg * 8) * 2));
#pragma unroll
        for (int i = 0; i < 4; ++i) {
            bf16x8 a = *(bf16x8*)(F1s + SWZ128(((w * 64 + 16 * i + lr) * 64 + ks * 32 + lg * 8) * 2));
#pragma unroll
            for (int j = 0; j < 4; ++j)
                acc2[i][j] = __builtin_amdgcn_mfma_f32_16x16x32_bf16(a, bv[j], acc2[i][j], 0, 0, 0);
        }
    }

    // store RAW h2pre + accumulate h2pre stats
#pragma unroll
    for (int j = 0; j < 4; ++j) {
        int c = 16 * j + lr;
        float s = 0.f, q = 0.f;
#pragma unroll
        for (int i = 0; i < 4; ++i)
#pragma unroll
            for (int r = 0; r < 4; ++r) {
                float v = acc2[i][j][r];
                s += v; q += v * v;
                long long gr = row0 + w * 64 + 16 * i + 4 * lg + r;
                H2[gr * 64 + c] = f2b(v);
            }
        s += __shfl_xor(s, 16); s += __shfl_xor(s, 32);
        q += __shfl_xor(q, 16); q += __shfl_xor(q, 32);
        if (lg == 0) {
            atomicAdd(&epiB[c * 2], s);
            atomicAdd(&epiB[c * 2 + 1], q);
        }
    }
    __syncthreads();
    if (tid < 128) atomicAdd(&sums[g * 1024 + tid], epiB[tid]);
}

// ------------------------------------------- MFMA chain: layers 3+4 -------
// SINGLE pass: h4pre stats + x3 (register partial max during bn3, shfl
// reduce -- no F3 re-read) + RAW per-point max of h4pre -> m4
// (max commutes with relu(bn4) since gamma4 = ones > 0).
__global__ __launch_bounds__(512, 2) void chain34_mfma(
    const bf16* __restrict__ H2, const bf16* __restrict__ w3b,
    const bf16* __restrict__ w4b, const float* __restrict__ p2,
    const float* __restrict__ p3, bf16* __restrict__ cat,
    float* __restrict__ sums, float* __restrict__ m4) {
    extern __shared__ char smem[];
    char* W3s = smem;                       // 16384  [128][64] bf16 swz128
    char* W4s = smem + 16384;               // 65536  [256][128] bf16 swz256
    char* A2s = smem + 81920;               // 16384  [128][64] bf16 swz128
    char* F3s = smem + 98304;               // 32768  [128][128] bf16 swz256
    float* P3s  = (float*)(smem + 131072);  // 1024 B (256 f32)
    float* epiS = (float*)(smem + 132096);  // 2048 B (512 f32) h4 stats
    float* P2s  = (float*)(smem + 134144);  // 512 B (128 f32)
    float* epiM = (float*)(smem + 134656);  // 8192 B (8 waves x 256 ch) x4 raw max
    float* epiX = (float*)(smem + 142848);  // 2048 B (4 pts x 128 ch) x3 max

    int tid = threadIdx.x;
    int w = tid >> 6, l = tid & 63, lg = l >> 4, lr = l & 15;
    long long rowB0 = (long long)blockIdx.x * 512;
    int g = (int)(rowB0 / SGr);

    for (int s = tid; s < 1024; s += 512)
        *(bf16x8*)(W3s + SWZ128(s * 16)) = *(const bf16x8*)(w3b + s * 8);
    for (int s = tid; s < 4096; s += 512)
        *(bf16x8*)(W4s + SWZ256(s * 16)) = *(const bf16x8*)(w4b + s * 8);
    if (tid < 256) P3s[tid] = p3[g * 1024 + tid];
    if (tid < 128) P2s[tid] = p2[g * 1024 + tid];
    epiS[tid & 511] = 0.f;
    __syncthreads();

    // bn3 params for this lane's 4 channels (c = 16w + 4lg + r)
    float sc3[4], sh3[4];
#pragma unroll
    for (int r = 0; r < 4; ++r) {
        int c = 16 * w + 4 * lg + r;
        sc3[r] = P3s[c * 2]; sh3[r] = P3s[c * 2 + 1];
    }

    for (int chunk = 0; chunk < 4; ++chunk) {
        long long row0 = rowB0 + chunk * 128;
        for (int s = tid; s < 1024; s += 512) {
            bf16x8 rv = *(const bf16x8*)(H2 + row0 * 64 + s * 8);
            int cb = (s & 7) * 8;
            bf16x8 ov;
#pragma unroll
            for (int e = 0; e < 8; ++e) {
                float v = fmaf(bs2f(rv[e]), P2s[(cb + e) * 2], P2s[(cb + e) * 2 + 1]);
                v = v > 0.f ? v : 0.f;
                ov[e] = f2bs(v);
            }
            *(bf16x8*)(A2s + SWZ128(s * 16)) = ov;
        }
        __syncthreads();

        // layer 3 (swapped operands): wave owns channels 16w..16w+15
        {
            f32x4 acc3[8] = {};
#pragma unroll
            for (int ks = 0; ks < 2; ++ks) {
                bf16x8 wf = *(bf16x8*)(W3s + SWZ128(((16 * w + lr) * 64 + ks * 32 + lg * 8) * 2));
#pragma unroll
                for (int j = 0; j < 8; ++j) {
                    bf16x8 a2 = *(bf16x8*)(A2s + SWZ128(((16 * j + lr) * 64 + ks * 32 + lg * 8) * 2));
                    acc3[j] = __builtin_amdgcn_mfma_f32_16x16x32_bf16(wf, a2, acc3[j], 0, 0, 0);
                }
            }
            // bn3+relu -> F3 (packed b64) + x3 partial max in registers
            // (row 16j+lr belongs to point j>>1; bf16 rounding is monotone
            //  so max-before-round == max-after-round)
            float xm[4][4];
#pragma unroll
            for (int p = 0; p < 4; ++p)
#pragma unroll
                for (int r = 0; r < 4; ++r) xm[p][r] = 0.f;
#pragma unroll
            for (int j = 0; j < 8; ++j) {
                s16x4 pk;
#pragma unroll
                for (int r = 0; r < 4; ++r) {
                    float v = fmaf(acc3[j][r], sc3[r], sh3[r]);
                    v = v > 0.f ? v : 0.f;
                    pk[r] = f2bs(v);
                    xm[j >> 1][r] = fmaxf(xm[j >> 1][r], v);
                }
                *(s16x4*)(F3s + SWZ256(((16 * j + lr) * 128 + 16 * w + 4 * lg) * 2)) = pk;
            }
            // complete 32-row max per point via lr-reduction (rows 32p+lr, 32p+16+lr)
#pragma unroll
            for (int p = 0; p < 4; ++p)
#pragma unroll
                for (int r = 0; r < 4; ++r) {
                    float m = xm[p][r];
                    m = fmaxf(m, __shfl_xor(m, 1));
                    m = fmaxf(m, __shfl_xor(m, 2));
                    m = fmaxf(m, __shfl_xor(m, 4));
                    m = fmaxf(m, __shfl_xor(m, 8));
                    if (lr == 0)
                        epiX[p * 128 + 16 * w + 4 * lg + r] = m;   // unique writer
                }
        }
        __syncthreads();   // F3 + epiX ready

        // layer 4: rows 16w..16w+15 per wave; B-frags from LDS W4s
        f32x4 acc4[16] = {};
#pragma unroll
        for (int ks = 0; ks < 4; ++ks) {
            bf16x8 a = *(bf16x8*)(F3s + SWZ256(((16 * w + lr) * 128 + ks * 32 + lg * 8) * 2));
#pragma unroll
            for (int j = 0; j < 16; ++j) {
                bf16x8 b = *(bf16x8*)(W4s + SWZ256(((16 * j + lr) * 128 + ks * 32 + lg * 8) * 2));
                acc4[j] = __builtin_amdgcn_mfma_f32_16x16x32_bf16(a, b, acc4[j], 0, 0, 0);
            }
        }

        // h4pre stats + raw per-wave max (channel c = 16j+lr)
#pragma unroll
        for (int j = 0; j < 16; ++j) {
            int c = 16 * j + lr;
            float s = acc4[j][0] + acc4[j][1] + acc4[j][2] + acc4[j][3];
            float q = acc4[j][0] * acc4[j][0] + acc4[j][1] * acc4[j][1] +
                      acc4[j][2] * acc4[j][2] + acc4[j][3] * acc4[j][3];
            float m = fmaxf(fmaxf(acc4[j][0], acc4[j][1]), fmaxf(acc4[j][2], acc4[j][3]));
            s += __shfl_xor(s, 16); s += __shfl_xor(s, 32);
            q += __shfl_xor(q, 16); q += __shfl_xor(q, 32);
            m = fmaxf(m, __shfl_xor(m, 16));
            m = fmaxf(m, __shfl_xor(m, 32));
            if (lg == 0) {
                atomicAdd(&epiS[c * 2], s);
                atomicAdd(&epiS[c * 2 + 1], q);
                epiM[w * 256 + c] = m;      // plain store: unique (w,c) writer
            }
        }
        // x3 -> cat from epiX (computed in registers during bn3)
        {
            long long pt0 = row0 >> 5;
            for (int e = tid; e < 512; e += 512) {
                int p = e >> 7, c = e & 127;
                cat[(pt0 + p) * 512 + 128 + c] = f2b(epiX[e]);
            }
        }
        __syncthreads();   // epiM ready; F3/A2/epiX reads complete

        // pair-reduce epiM (2 waves per point) -> raw m4
        {
            long long pt0 = row0 >> 5;
            for (int e = tid; e < 1024; e += 512) {
                int p = e >> 8, c = e & 255;
                float m = fmaxf(epiM[(2 * p) * 256 + c], epiM[(2 * p + 1) * 256 + c]);
                m4[(pt0 + p) * 256 + c] = m;
            }
        }
        __syncthreads();   // epiM reads done before next chunk overwrites
    }
    atomicAdd(&sums[g * 1024 + (tid & 511)], tid < 512 ? epiS[tid] : 0.f);
}

// ----------------------- x4 finalize: relu(bn4(m4)) -> cat[256..512] ------
__global__ __launch_bounds__(256) void x4_finalize(const float* __restrict__ m4,
                                                   const float* __restrict__ p4,
                                                   bf16* __restrict__ cat) {
    int row = blockIdx.x;          // g*BNr + pt
    int c = threadIdx.x;
    int g = row / BNr;
    float v = fmaf(m4[(size_t)row * 256 + c], p4[(g * 512 + c) * 2], p4[(g * 512 + c) * 2 + 1]);
    v = v > 0.f ? v : 0.f;
    cat[(size_t)row * 512 + 256 + c] = f2b(v);
}

// ----------------------------------------------------- generic MFMA GEMM --
// BNA=1: bn(pba)+relu on A during staging + x2 maxes -> cat (blockIdx.y==0).
// MODE 0: store f32. MODE 1: stats only. MODE 3: store f32 AND stats.
template <int MODE, int CH, int BNA>
__global__ __launch_bounds__(256, 4) void mfma_gemm(
    const bf16* __restrict__ A, const bf16* __restrict__ Wt,
    float* __restrict__ OutF, bf16* __restrict__ OutB,
    int Cin, int ldOut, long long sA, long long sW, long long sO,
    int rowsPerGroup, const float* __restrict__ params, float* __restrict__ sums,
    const float* __restrict__ pba, bf16* __restrict__ cat) {
    __shared__ char As[16384];   // [128][64] bf16 swz128
    __shared__ char Bs[8192];    // [64][64] bf16 swz128
    __shared__ float epi[128];
    __shared__ float PBs[128];
    __shared__ int x2m[256];     // [4 pts][64 ch]
    int tid = threadIdx.x;
    int w = tid >> 6, l = tid & 63, lg = l >> 4, lr = l & 15;
    int bz = blockIdx.z;
    const bf16* Ap = A + (long long)bz * sA;
    const bf16* Wp = Wt + (long long)bz * sW;
    int o0 = blockIdx.y * 64;
    long long rowB0 = (long long)blockIdx.x * (128 * CH);
    int g = (int)(rowB0 / rowsPerGroup);
    if ((MODE == 1 || MODE == 3) && tid < 128) epi[tid] = 0.f;
    if (BNA && tid < 128) PBs[tid] = pba[g * 1024 + tid];
    int wr = (w >> 1) * 64, wc = (w & 1) * 32;

    for (int ch = 0; ch < CH; ++ch) {
        long long row0 = rowB0 + (long long)ch * 128;
        if (BNA) {
            __syncthreads();
            if (tid < 256) x2m[tid] = 0;
        }
        f32x4 acc[4][2] = {};
        for (int k0 = 0; k0 < Cin; k0 += 64) {
            __syncthreads();
            for (int s = tid; s < 1024; s += 256) {
                if (BNA) {
                    bf16x8 rv = *(const bf16x8*)(Ap + (row0 + (s >> 3)) * Cin + k0 + (s & 7) * 8);
                    int cb = k0 + (s & 7) * 8;
                    int pt = (s >> 3) >> 5;
                    bf16x8 ov;
#pragma unroll
                    for (int e = 0; e < 8; ++e) {
                        float v = fmaf(bs2f(rv[e]), PBs[(cb + e) * 2], PBs[(cb + e) * 2 + 1]);
                        v = v > 0.f ? v : 0.f;
                        ov[e] = f2bs(v);
                        atomicMax(&x2m[pt * 64 + cb + e], __float_as_int(v));
                    }
                    *(bf16x8*)(As + SWZ128(s * 16)) = ov;
                } else {
                    *(bf16x8*)(As + SWZ128(s * 16)) =
                        *(const bf16x8*)(Ap + (row0 + (s >> 3)) * Cin + k0 + (s & 7) * 8);
                }
            }
            for (int s = tid; s < 512; s += 256)
                *(bf16x8*)(Bs + SWZ128(s * 16)) =
                    *(const bf16x8*)(Wp + (long long)(o0 + (s >> 3)) * Cin + k0 + (s & 7) * 8);
            __syncthreads();
#pragma unroll
            for (int ks = 0; ks < 2; ++ks) {
                bf16x8 b0 = *(bf16x8*)(Bs + SWZ128(((wc + lr) * 64 + ks * 32 + lg * 8) * 2));
                bf16x8 b1 = *(bf16x8*)(Bs + SWZ128(((wc + 16 + lr) * 64 + ks * 32 + lg * 8) * 2));
#pragma unroll
                for (int i = 0; i < 4; ++i) {
                    bf16x8 a = *(bf16x8*)(As + SWZ128(((wr + 16 * i + lr) * 64 + ks * 32 + lg * 8) * 2));
                    acc[i][0] = __builtin_amdgcn_mfma_f32_16x16x32_bf16(a, b0, acc[i][0], 0, 0, 0);
                    acc[i][1] = __builtin_amdgcn_mfma_f32_16x16x32_bf16(a, b1, acc[i][1], 0, 0, 0);
                }
            }
        }
        if (BNA && blockIdx.y == 0) {
            long long pt0 = row0 >> 5;
            if (tid < 256) {
                int p = tid >> 6, c = tid & 63;
                cat[(pt0 + p) * 512 + 64 + c] = f2b(__int_as_float(x2m[tid]));
            }
        }
        if (MODE == 1 || MODE == 3) {
#pragma unroll
            for (int j = 0; j < 2; ++j) {
                int c = wc + 16 * j + lr;
                float s = 0.f, q = 0.f;
#pragma unroll
                for (int i = 0; i < 4; ++i)
#pragma unroll
                    for (int r = 0; r < 4; ++r) {
                        float v = acc[i][j][r];
                        s += v; q += v * v;
                    }
                s += __shfl_xor(s, 16); s += __shfl_xor(s, 32);
                q += __shfl_xor(q, 16); q += __shfl_xor(q, 32);
                if (lg == 0) {
                    atomicAdd(&epi[c * 2], s);
                    atomicAdd(&epi[c * 2 + 1], q);
                }
            }
        }
        if (MODE == 0 || MODE == 3) {
            float* Op = OutF + (long long)bz * sO;
#pragma unroll
            for (int j = 0; j < 2; ++j) {
                int gc = o0 + wc + 16 * j + lr;
#pragma unroll
                for (int i = 0; i < 4; ++i)
#pragma unroll
                    for (int r = 0; r < 4; ++r) {
                        long long gr = row0 + wr + 16 * i + 4 * lg + r;
                        Op[gr * ldOut + gc] = acc[i][j][r];
                    }
            }
        }
    }
    if (MODE == 1 || MODE == 3) {
        __syncthreads();
        if (tid < 128) atomicAdd(&sums[g * 1024 + o0 * 2 + tid], epi[tid]);
    }
}

// --------------------------------- l5 finalize: bn+relu -> embB + norms ---
__global__ __launch_bounds__(256) void emb_finalize(const float* __restrict__ h5,
                                                    const float* __restrict__ p5,
                                                    bf16* __restrict__ embB,
                                                    float* __restrict__ nrm) {
    __shared__ float red[256];
    int row = blockIdx.x; int t = threadIdx.x;
    int g = row / BNr;
    float s = 0.f;
#pragma unroll
    for (int i = 0; i < 2; ++i) {
        int c = t + i * 256;
        float v = fmaf(h5[(size_t)row * 512 + c], p5[(g * 512 + c) * 2], p5[(g * 512 + c) * 2 + 1]);
        v = v > 0.f ? v : 0.f;
        bf16 bb = f2b(v);
        embB[(size_t)row * 512 + c] = bb;
        float vb = b2f(bb);
        s += vb * vb;
    }
    red[t] = s; __syncthreads();
    for (int st = 128; st > 0; st >>= 1) { if (t < st) red[t] += red[t + st]; __syncthreads(); }
    if (t == 0) nrm[row] = red[0];
}

// -------------------------------- distance + softmax + weighted sum -------
__global__ __launch_bounds__(256) void corr_kernel(const float* __restrict__ inner,
                                                   const float* __restrict__ nrm,
                                                   const float* __restrict__ tgt,
                                                   float* __restrict__ out) {
    __shared__ float red[256];
    int blk = blockIdx.x;                 // b*N + n
    int b = blk >> 11, n = blk & (NN - 1);
    int t = threadIdx.x;
    const float* inr = inner + ((size_t)b * NN + n) * NN;
    float xx = nrm[b * NN + n];
    float dloc[8];
    float vmax = -INFINITY;
#pragma unroll
    for (int i = 0; i < 8; ++i) {
        int m = t + i * 256;
        float pd = (xx - 2.f * inr[m]) + nrm[BNr + b * NN + m];
        float d = pd > 0.f ? sqrtf(pd) : 0.f;
        dloc[i] = d;
        vmax = fmaxf(vmax, -d);
    }
    red[t] = vmax; __syncthreads();
    for (int s = 128; s > 0; s >>= 1) { if (t < s) red[t] = fmaxf(red[t], red[t + s]); __syncthreads(); }
    vmax = red[0]; __syncthreads();
    const float* tp = tgt + (size_t)b * 3 * NN;
    float se = 0.f, s0 = 0.f, s1 = 0.f, s2 = 0.f;
#pragma unroll
    for (int i = 0; i < 8; ++i) {
        int m = t + i * 256;
        float p = expf(-dloc[i] - vmax);
        se += p;
        s0 += p * tp[m]; s1 += p * tp[NN + m]; s2 += p * tp[2 * NN + m];
    }
    red[t] = se; __syncthreads();
    for (int s = 128; s > 0; s >>= 1) { if (t < s) red[t] += red[t + s]; __syncthreads(); }
    float tot = red[0]; __syncthreads();
    red[t] = s0; __syncthreads();
    for (int s = 128; s > 0; s >>= 1) { if (t < s) red[t] += red[t + s]; __syncthreads(); }
    float o0v = red[0]; __syncthreads();
    red[t] = s1; __syncthreads();
    for (int s = 128; s > 0; s >>= 1) { if (t < s) red[t] += red[t + s]; __syncthreads(); }
    float o1v = red[0]; __syncthreads();
    red[t] = s2; __syncthreads();
    for (int s = 128; s > 0; s >>= 1) { if (t < s) red[t] += red[t + s]; __syncthreads(); }
    float o2v = red[0];
    if (t == 0) {
        out[(size_t)b * 3 * NN + n]          = o0v / tot;
        out[(size_t)b * 3 * NN + NN + n]     = o1v / tot;
        out[(size_t)b * 3 * NN + 2 * NN + n] = o2v / tot;
    }
}

// ------------------------------------------------------------- driver -----
extern "C" void kernel_launch(void* const* d_in, const int* in_sizes, int n_in,
                              void* d_out, int out_size, void* d_ws, size_t ws_size,
                              hipStream_t stream) {
    const float* src = (const float*)d_in[0];
    const float* tgt = (const float*)d_in[1];
    const float* w1  = (const float*)d_in[2];
    const float* w2  = (const float*)d_in[3];
    const float* w3  = (const float*)d_in[4];
    const float* w4  = (const float*)d_in[5];
    const float* w5  = (const float*)d_in[6];
    const float* g1  = (const float*)d_in[7];
    const float* g2  = (const float*)d_in[8];
    const float* g3  = (const float*)d_in[9];
    const float* g4  = (const float*)d_in[10];
    const float* g5  = (const float*)d_in[11];
    const float* b1  = (const float*)d_in[12];
    const float* b2  = (const float*)d_in[13];
    const float* b3  = (const float*)d_in[14];
    const float* b4  = (const float*)d_in[15];
    const float* b5  = (const float*)d_in[16];
    float* out = (float*)d_out;
    char* ws = (char*)d_ws;
    (void)in_sizes; (void)n_in;

    size_t off = 0;
    auto alloc = [&](size_t bytes) { size_t o = off; off = (off + bytes + 255) & ~(size_t)255; return o; };
    int*   idx    = (int*)(ws + alloc((size_t)SR * 4));                 // 2 MB
    bf16*  H2     = (bf16*)(ws + alloc((size_t)SR * 64 * 2));           // 64 MB (overlay inner f32)
    bf16*  cat    = (bf16*)(ws + alloc((size_t)GG * BNr * 512 * 2));    // 16 MB
    bf16*  embB   = (bf16*)(ws + alloc((size_t)GG * BNr * 512 * 2));    // 16 MB
    float* h5     = (float*)(ws + alloc((size_t)GG * BNr * 512 * 4));   // 33.5 MB
    float* m4     = (float*)(ws + alloc((size_t)GG * BNr * 256 * 4));   // 16.8 MB
    float* nrm    = (float*)(ws + alloc((size_t)GG * BNr * 4));
    float* sums   = (float*)(ws + alloc(2048 * 4));
    float* g1s    = (float*)(ws + alloc(64 * 4));
    float* g1part = (float*)(ws + alloc((size_t)GG * 2048 * 32 * 4));   // 512 KB
    float* prm    = (float*)(ws + alloc(5 * 2048 * 4));
    bf16*  w2b    = (bf16*)(ws + alloc(4096 * 2));
    bf16*  w3b    = (bf16*)(ws + alloc(8192 * 2));
    bf16*  w4b    = (bf16*)(ws + alloc(32768 * 2));
    bf16*  w5b    = (bf16*)(ws + alloc(262144 * 2));
    float* P1 = prm, *P2 = prm + 2048, *P3 = prm + 4096, *P4 = prm + 6144, *P5 = prm + 8192;
    float* inner = (float*)H2;   // overlay: SR*64*2 bytes == B*N*N*4 bytes exactly

    if (ws_size < off) {
        hipMemsetAsync(d_out, 0, (size_t)out_size * 4, stream);
        return;
    }

    zero_kernel<<<8, 256, 0, stream>>>(sums, 2048);   // first-call poison guard
    knn_kernel<<<GG * BB * NN / 4, 256, 0, stream>>>(src, tgt, idx, g1part);
    cvt_all_kernel<<<1024, 256, 0, stream>>>(w2, w3, w4, w5, w2b, w3b, w4b, w5b);

    // layer-1 BN params: reduce knn's Gram partials, then finalize
    reduce_g1_kernel<<<GG * 27, 256, 0, stream>>>(g1part, g1s);
    finalize_l1_kernel<<<1, 128, 0, stream>>>(g1s, w1, g1, b1, (float)SGr, P1);

    // apply pass: F1+x1, l2 -> raw h2pre (H2) + h2 stats
    l12_mfma<<<SR / 256, 256, 0, stream>>>(src, tgt, w1, w2b, idx, P1, H2, cat, sums);
    finalize_bn_kernel<<<1, 128, 0, stream>>>(sums, 64, g2, b2, (float)SGr, P2);

    // layer 3 stats (bn2-on-load of raw H2) + x2 -> cat
    mfma_gemm<1, 4, 1><<<dim3(SR / 512, 2, 1), 256, 0, stream>>>(
        H2, w3b, nullptr, nullptr, 64, 0, 0, 0, 0, SGr, nullptr, sums, P2, cat);
    finalize_bn_kernel<<<2, 128, 0, stream>>>(sums, 128, g3, b3, (float)SGr, P3);

    // layers 3+4 chain: SINGLE pass (h4 stats + x3 + raw m4)
    chain34_mfma<<<1024, 512, 144896, stream>>>(H2, w3b, w4b, P2, P3, cat, sums, m4);
    finalize_bn_kernel<<<4, 128, 0, stream>>>(sums, 256, g4, b4, (float)SGr, P4);
    x4_finalize<<<GG * BNr, 256, 0, stream>>>(m4, P4, cat);

    // layer 5: single GEMM pass (raw h5 f32 + stats), then fused finalize
    mfma_gemm<3, 1, 0><<<dim3(GG * BNr / 128, 8, 1), 256, 0, stream>>>(
        cat, w5b, h5, nullptr, 512, 512, 0, 0, 0, BNr, nullptr, sums, nullptr, nullptr);
    finalize_bn_kernel<<<8, 128, 0, stream>>>(sums, 512, g5, b5, (float)BNr, P5);
    emb_finalize<<<GG * BNr, 256, 0, stream>>>(h5, P5, embB, nrm);

    // inner products: per-batch embB_src x embB_tgt^T -> inner (overlay on H2)
    mfma_gemm<0, 1, 0><<<dim3(NN / 128, NN / 64, BB), 256, 0, stream>>>(
        embB, embB + (size_t)BNr * 512, inner, nullptr, 512, 2048,
        (long long)NN * 512, (long long)NN * 512, (long long)NN * NN,
        SGr, nullptr, nullptr, nullptr, nullptr);

    // distance + softmax + weighted sum of tgt points
    corr_kernel<<<BB * NN, 256, 0, stream>>>(inner, nrm, tgt, out);
}

// Round 20
// 594.966 us; speedup vs baseline: 1.0238x; 1.0238x over previous
//
#include <hip/hip_runtime.h>
#include <hip/hip_bf16.h>
#include <math.h>

#define BB 4
#define NN 2048
#define KK 32
#define GG 2
constexpr int BNr = BB * NN;       // 8192 point-rows per group
constexpr int SGr = BB * NN * KK;  // 262144 sample rows per group
constexpr int SR  = GG * SGr;      // 524288 total sample rows

typedef __hip_bfloat16 bf16;
typedef __attribute__((ext_vector_type(8))) short bf16x8;
typedef __attribute__((ext_vector_type(4))) short s16x4;
typedef __attribute__((ext_vector_type(4))) float f32x4;
__device__ __forceinline__ float b2f(bf16 v) { return __bfloat162float(v); }
__device__ __forceinline__ bf16  f2b(float v) { return __float2bfloat16(v); }
__device__ __forceinline__ short f2bs(float v) { bf16 b = f2b(v); return *(short*)&b; }
__device__ __forceinline__ float bs2f(short s) { bf16 b; *(short*)&b = s; return b2f(b); }

// XOR swizzles for LDS tiles (byte-offset based; row = stride 128B / 256B)
#define SWZ128(b) ((b) ^ ((((b) >> 7) & 7) << 4))
#define SWZ256(b) ((b) ^ ((((b) >> 8) & 7) << 4))

// ------------------------------------------------- kNN (wave-per-query) ---
// + fused layer-1 feature Gram -> per-block partials (no global atomics).
__global__ __launch_bounds__(256) void knn_kernel(const float* __restrict__ src,
                                                  const float* __restrict__ tgt,
                                                  int* __restrict__ idx_out,
                                                  float* __restrict__ g1part) {
    __shared__ float pts[3 * NN];   // 24 KB
    __shared__ float xxs[NN];       // 8 KB
    __shared__ int   sel[4][32];
    __shared__ float Gs[27];
    int blk = blockIdx.x;           // (g*B+b)*(NN/4) + chunk
    int gb = blk >> 9;              // / (NN/4)
    int chunk = blk & 511;
    int g = gb >> 2, b = gb & 3;
    const float* x = (g == 0 ? src : tgt) + (size_t)b * 3 * NN;
    int t = threadIdx.x;
    if (t < 27) Gs[t] = 0.f;
    for (int i = t; i < 3 * NN; i += 256) pts[i] = x[i];
    __syncthreads();
    for (int m = t; m < NN; m += 256) {
        float p0 = pts[m], p1 = pts[NN + m], p2 = pts[2 * NN + m];
        xxs[m] = p0 * p0 + p1 * p1 + p2 * p2;
    }
    __syncthreads();
    int w = t >> 6, l = t & 63;
    int n = chunk * 4 + w;
    float q0 = pts[n], q1 = pts[NN + n], q2 = pts[2 * NN + n];
    float xxn = xxs[n];
    float d2[32];
#pragma unroll
    for (int s = 0; s < 32; ++s) {
        int m = s * 64 + l;
        float dot = q0 * pts[m] + q1 * pts[NN + m] + q2 * pts[2 * NN + m];
        d2[s] = (xxn - 2.0f * dot) + xxs[m];
    }
    // cached group minima (4 groups x 8 slots)
    float gval[4]; int gslot[4];
#pragma unroll
    for (int G = 0; G < 4; ++G) {
        float v = d2[G * 8]; int sl = G * 8;
#pragma unroll
        for (int s = 1; s < 8; ++s)
            if (d2[G * 8 + s] < v) { v = d2[G * 8 + s]; sl = G * 8 + s; }
        gval[G] = v; gslot[G] = sl;
    }
    int* outp = idx_out + ((size_t)gb * NN + n) * KK;
    for (int k = 0; k < KK; ++k) {
        float bv = fminf(fminf(gval[0], gval[1]), fminf(gval[2], gval[3]));
        float gv = bv;
#pragma unroll
        for (int off = 1; off < 64; off <<= 1) gv = fminf(gv, __shfl_xor(gv, off));
        unsigned long long mask = __ballot(bv == gv);
        int winner = (int)__builtin_ctzll(mask);
        if (l == winner) {
            int grp = (gval[0] == gv) ? 0 : (gval[1] == gv) ? 1 : (gval[2] == gv) ? 2 : 3;
#pragma unroll
            for (int G = 0; G < 4; ++G)
                if (G == grp) {
                    int bs = gslot[G];
                    outp[k] = bs * 64 + l;
                    sel[w][k] = bs * 64 + l;
#pragma unroll
                    for (int s = 0; s < 8; ++s)
                        if (G * 8 + s == bs) d2[G * 8 + s] = INFINITY;
                    float v = d2[G * 8]; int sl = G * 8;
#pragma unroll
                    for (int s = 1; s < 8; ++s)
                        if (d2[G * 8 + s] < v) { v = d2[G * 8 + s]; sl = G * 8 + s; }
                    gval[G] = v; gslot[G] = sl;
                }
        }
    }
    __syncthreads();   // sel visible across lanes
    // feature Gram accumulation (layer-1 BN stats)
    float nx = 0.f, ny = 0.f, nz = 0.f;
    if (l < 32) {
        int m = sel[w][l];
        nx = pts[m]; ny = pts[NN + m]; nz = pts[2 * NN + m];
    }
    float v9[9] = {nx * nx, nx * ny, nx * nz, ny * ny, ny * nz, nz * nz, nx, ny, nz};
#pragma unroll
    for (int e = 0; e < 9; ++e) {
#pragma unroll
        for (int off = 1; off < 64; off <<= 1) v9[e] += __shfl_xor(v9[e], off);
    }
    if (l == 0) {
        float c3[3] = {q0, q1, q2};
#pragma unroll
        for (int e = 0; e < 6; ++e) atomicAdd(&Gs[e], v9[e]);
#pragma unroll
        for (int a = 0; a < 3; ++a)
#pragma unroll
            for (int bb = 0; bb < 3; ++bb)
                atomicAdd(&Gs[6 + a * 3 + bb], v9[6 + a] * c3[bb]);
        atomicAdd(&Gs[15], 32.f * q0 * q0);
        atomicAdd(&Gs[16], 32.f * q0 * q1);
        atomicAdd(&Gs[17], 32.f * q0 * q2);
        atomicAdd(&Gs[18], 32.f * q1 * q1);
        atomicAdd(&Gs[19], 32.f * q1 * q2);
        atomicAdd(&Gs[20], 32.f * q2 * q2);
        atomicAdd(&Gs[21], v9[6]);
        atomicAdd(&Gs[22], v9[7]);
        atomicAdd(&Gs[23], v9[8]);
        atomicAdd(&Gs[24], 32.f * q0);
        atomicAdd(&Gs[25], 32.f * q1);
        atomicAdd(&Gs[26], 32.f * q2);
    }
    __syncthreads();
    if (t < 27) g1part[(size_t)blk * 32 + t] = Gs[t];   // plain store, no atomics
}

// reduce per-block Gram partials: 54 blocks, one (g,e) each
__global__ __launch_bounds__(256) void reduce_g1_kernel(const float* __restrict__ part,
                                                        float* __restrict__ g1s) {
    __shared__ float red[256];
    int bx = blockIdx.x;
    int g = bx / 27, e = bx - g * 27;
    int t = threadIdx.x;
    float s = 0.f;
    for (int b = t; b < 2048; b += 256) s += part[((size_t)g * 2048 + b) * 32 + e];
    red[t] = s; __syncthreads();
    for (int st = 128; st > 0; st >>= 1) { if (t < st) red[t] += red[t + st]; __syncthreads(); }
    if (t == 0) g1s[g * 27 + e] = red[0];
}

// ---------------------------------------------------------------- misc ----
__global__ void zero_kernel(float* __restrict__ p, int n) {
    int i = blockIdx.x * 256 + threadIdx.x;
    if (i < n) p[i] = 0.f;
}

__global__ void cvt_all_kernel(const float* __restrict__ w2, const float* __restrict__ w3,
                               const float* __restrict__ w4, const float* __restrict__ w5,
                               bf16* __restrict__ w2b, bf16* __restrict__ w3b,
                               bf16* __restrict__ w4b, bf16* __restrict__ w5b) {
    int i = blockIdx.x * 256 + threadIdx.x;
    if (i < 4096)   w2b[i] = f2b(w2[i]);
    if (i < 8192)   w3b[i] = f2b(w3[i]);
    if (i < 32768)  w4b[i] = f2b(w4[i]);
    if (i < 262144) w5b[i] = f2b(w5[i]);
}

// finalize: compute scale/shift and zero the consumed sums for the next stage
__global__ void finalize_bn_kernel(float* __restrict__ sums, int C,
                                   const float* __restrict__ gamma,
                                   const float* __restrict__ beta,
                                   float cnt, float* __restrict__ params) {
    int i = blockIdx.x * blockDim.x + threadIdx.x;
    if (i >= GG * C) return;
    int g = i / C, c = i - g * C;
    float s  = sums[(g * 512 + c) * 2 + 0];
    float sq = sums[(g * 512 + c) * 2 + 1];
    float mean = s / cnt;
    float var = sq / cnt - mean * mean;
    if (var < 0.f) var = 0.f;
    float sc = gamma[c] * rsqrtf(var + 1e-5f);
    params[(g * 512 + c) * 2 + 0] = sc;
    params[(g * 512 + c) * 2 + 1] = beta[c] - mean * sc;
    sums[(g * 512 + c) * 2 + 0] = 0.f;
    sums[(g * 512 + c) * 2 + 1] = 0.f;
}

// layer-1 BN params from feature Gram: s = w.fsum, q = w^T G w
__global__ void finalize_l1_kernel(const float* __restrict__ g1s,
                                   const float* __restrict__ w1,
                                   const float* __restrict__ gamma,
                                   const float* __restrict__ beta,
                                   float cnt, float* __restrict__ params) {
    int i = blockIdx.x * blockDim.x + threadIdx.x;
    if (i >= GG * 64) return;
    int g = i >> 6, o = i & 63;
    const float* G = g1s + g * 27;
    float wv[6];
#pragma unroll
    for (int c = 0; c < 6; ++c) wv[c] = w1[o * 6 + c];
    float s = wv[0] * G[21] + wv[1] * G[22] + wv[2] * G[23] +
              wv[3] * G[24] + wv[4] * G[25] + wv[5] * G[26];
    const int UT[6][6] = {{0, 1, 2, 6, 7, 8},   {1, 3, 4, 9, 10, 11},
                          {2, 4, 5, 12, 13, 14},{6, 9, 12, 15, 16, 17},
                          {7, 10, 13, 16, 18, 19},{8, 11, 14, 17, 19, 20}};
    float q = 0.f;
#pragma unroll
    for (int a = 0; a < 6; ++a)
#pragma unroll
        for (int bb = 0; bb < 6; ++bb) q += wv[a] * wv[bb] * G[UT[a][bb]];
    float mean = s / cnt;
    float var = q / cnt - mean * mean;
    if (var < 0.f) var = 0.f;
    float sc = gamma[o] * rsqrtf(var + 1e-5f);
    params[(g * 512 + o) * 2 + 0] = sc;
    params[(g * 512 + o) * 2 + 1] = beta[o] - mean * sc;
}

// ----------------------------------------------- MFMA layers 1+2 ----------
// Apply pass only: gather -> l1 MFMA -> bn1+relu -> F1 (LDS) + x1 -> cat,
// l2 MFMA -> store RAW h2pre -> H2, accumulate h2pre stats -> sums.
__global__ __launch_bounds__(256, 3) void l12_mfma(
    const float* __restrict__ src, const float* __restrict__ tgt,
    const float* __restrict__ w1, const bf16* __restrict__ w2b,
    const int* __restrict__ idx, const float* __restrict__ p1,
    bf16* __restrict__ H2, bf16* __restrict__ cat, float* __restrict__ sums) {
    __shared__ char F1s[32768];    // [256][64] bf16 swz128
    __shared__ char W2s[8192];     // [64][64] bf16 swz128
    __shared__ float epiA[512];    // x1 int-max [8][64]
    __shared__ float epiB[128];    // h2 stats [64][2]
    int tid = threadIdx.x;
    int w = tid >> 6, l = tid & 63, lg = l >> 4, lr = l & 15;
    long long row0 = (long long)blockIdx.x * 256;
    int g = (int)(row0 / SGr);

    epiA[tid] = 0.f; epiA[tid + 256] = 0.f;
    if (tid < 128) epiB[tid] = 0.f;
    for (int s = tid; s < 512; s += 256)
        *(bf16x8*)(W2s + SWZ128(s * 16)) = *(const bf16x8*)(w2b + s * 8);

    bf16x8 af[4];
#pragma unroll
    for (int i = 0; i < 4; ++i) {
        af[i] = (bf16x8){0, 0, 0, 0, 0, 0, 0, 0};
        if (lg == 0) {
            int rr = (int)row0 + w * 64 + 16 * i + lr;
            int nrow = rr >> 5;
            int n = nrow & (NN - 1);
            int gb = nrow >> 11;
            int b = gb & 3, gg = gb >> 2;
            const float* x = (gg ? tgt : src) + (size_t)b * 3 * NN;
            int j = idx[rr];
            af[i][0] = f2bs(x[j]);
            af[i][1] = f2bs(x[NN + j]);
            af[i][2] = f2bs(x[2 * NN + j]);
            af[i][3] = f2bs(x[n]);
            af[i][4] = f2bs(x[NN + n]);
            af[i][5] = f2bs(x[2 * NN + n]);
        }
    }
    bf16x8 bf1[4];
#pragma unroll
    for (int j = 0; j < 4; ++j) {
        bf1[j] = (bf16x8){0, 0, 0, 0, 0, 0, 0, 0};
        if (lg == 0) {
            int o = 16 * j + lr;
#pragma unroll
            for (int c = 0; c < 6; ++c) bf1[j][c] = f2bs(w1[o * 6 + c]);
        }
    }

    f32x4 acc1[4][4] = {};
#pragma unroll
    for (int i = 0; i < 4; ++i)
#pragma unroll
        for (int j = 0; j < 4; ++j)
            acc1[i][j] = __builtin_amdgcn_mfma_f32_16x16x32_bf16(af[i], bf1[j], acc1[i][j], 0, 0, 0);

    __syncthreads();

    // bn1 + relu -> F1 (bf16) + x1 max
#pragma unroll
    for (int j = 0; j < 4; ++j) {
        int c = 16 * j + lr;
        float sc = p1[(g * 512 + c) * 2], sh = p1[(g * 512 + c) * 2 + 1];
#pragma unroll
        for (int i = 0; i < 4; ++i) {
            float m = 0.f;
#pragma unroll
            for (int r = 0; r < 4; ++r) {
                float v = fmaf(acc1[i][j][r], sc, sh);
                v = v > 0.f ? v : 0.f;
                m = fmaxf(m, v);
                int rowi = w * 64 + 16 * i + 4 * lg + r;
                *(bf16*)(F1s + SWZ128((rowi * 64 + c) * 2)) = f2b(v);
            }
            int p = 2 * w + (i >> 1);
            atomicMax((int*)epiA + p * 64 + c, __float_as_int(m));
        }
    }
    __syncthreads();

    {
        long long pt0 = row0 >> 5;
        for (int e = tid; e < 512; e += 256) {
            int p = e >> 6, c = e & 63;
            cat[(pt0 + p) * 512 + c] = f2b(__int_as_float(((int*)epiA)[p * 64 + c]));
        }
    }

    // layer 2 MFMA: F1 @ w2^T
    f32x4 acc2[4][4] = {};
#pragma unroll
    for (int ks = 0; ks < 2; ++ks) {
        bf16x8 bv[4];
#pragma unroll
        for (int j = 0; j < 4; ++j)
            bv[j] = *(bf16x8*)(W2s + SWZ128(((16 * j + lr) * 64 + ks * 32 + lg * 8) * 2));
#pragma unroll
        for (int i = 0; i < 4; ++i) {
            bf16x8 a = *(bf16x8*)(F1s + SWZ128(((w * 64 + 16 * i + lr) * 64 + ks * 32 + lg * 8) * 2));
#pragma unroll
            for (int j = 0; j < 4; ++j)
                acc2[i][j] = __builtin_amdgcn_mfma_f32_16x16x32_bf16(a, bv[j], acc2[i][j], 0, 0, 0);
        }
    }

    // store RAW h2pre + accumulate h2pre stats
#pragma unroll
    for (int j = 0; j < 4; ++j) {
        int c = 16 * j + lr;
        float s = 0.f, q = 0.f;
#pragma unroll
        for (int i = 0; i < 4; ++i)
#pragma unroll
            for (int r = 0; r < 4; ++r) {
                float v = acc2[i][j][r];
                s += v; q += v * v;
                long long gr = row0 + w * 64 + 16 * i + 4 * lg + r;
                H2[gr * 64 + c] = f2b(v);
            }
        s += __shfl_xor(s, 16); s += __shfl_xor(s, 32);
        q += __shfl_xor(q, 16); q += __shfl_xor(q, 32);
        if (lg == 0) {
            atomicAdd(&epiB[c * 2], s);
            atomicAdd(&epiB[c * 2 + 1], q);
        }
    }
    __syncthreads();
    if (tid < 128) atomicAdd(&sums[g * 1024 + tid], epiB[tid]);
}

// ------------------------------------------- MFMA chain: layers 3+4 -------
// SINGLE pass (r18 proven): h4pre stats + x3 (scalar F3 re-read -- 32
// independent pipelined LDS loads beat dependent shfl chains, r19 lesson) +
// RAW per-point max of h4pre -> m4 (max commutes with relu(bn4), gamma4>0).
__global__ __launch_bounds__(512, 2) void chain34_mfma(
    const bf16* __restrict__ H2, const bf16* __restrict__ w3b,
    const bf16* __restrict__ w4b, const float* __restrict__ p2,
    const float* __restrict__ p3, bf16* __restrict__ cat,
    float* __restrict__ sums, float* __restrict__ m4) {
    extern __shared__ char smem[];
    char* W3s = smem;                       // 16384  [128][64] bf16 swz128
    char* W4s = smem + 16384;               // 65536  [256][128] bf16 swz256
    char* A2s = smem + 81920;               // 16384  [128][64] bf16 swz128
    char* F3s = smem + 98304;               // 32768  [128][128] bf16 swz256
    float* P3s  = (float*)(smem + 131072);  // 1024 B (256 f32)
    float* epiS = (float*)(smem + 132096);  // 2048 B (512 f32) h4 stats
    float* P2s  = (float*)(smem + 134144);  // 512 B (128 f32)
    float* epiM = (float*)(smem + 134656);  // 8192 B (8 waves x 256 ch) x4 raw max

    int tid = threadIdx.x;
    int w = tid >> 6, l = tid & 63, lg = l >> 4, lr = l & 15;
    long long rowB0 = (long long)blockIdx.x * 512;
    int g = (int)(rowB0 / SGr);

    for (int s = tid; s < 1024; s += 512)
        *(bf16x8*)(W3s + SWZ128(s * 16)) = *(const bf16x8*)(w3b + s * 8);
    for (int s = tid; s < 4096; s += 512)
        *(bf16x8*)(W4s + SWZ256(s * 16)) = *(const bf16x8*)(w4b + s * 8);
    if (tid < 256) P3s[tid] = p3[g * 1024 + tid];
    if (tid < 128) P2s[tid] = p2[g * 1024 + tid];
    epiS[tid & 511] = 0.f;
    __syncthreads();

    // bn3 params for this lane's 4 channels (c = 16w + 4lg + r)
    float sc3[4], sh3[4];
#pragma unroll
    for (int r = 0; r < 4; ++r) {
        int c = 16 * w + 4 * lg + r;
        sc3[r] = P3s[c * 2]; sh3[r] = P3s[c * 2 + 1];
    }

    for (int chunk = 0; chunk < 4; ++chunk) {
        long long row0 = rowB0 + chunk * 128;
        for (int s = tid; s < 1024; s += 512) {
            bf16x8 rv = *(const bf16x8*)(H2 + row0 * 64 + s * 8);
            int cb = (s & 7) * 8;
            bf16x8 ov;
#pragma unroll
            for (int e = 0; e < 8; ++e) {
                float v = fmaf(bs2f(rv[e]), P2s[(cb + e) * 2], P2s[(cb + e) * 2 + 1]);
                v = v > 0.f ? v : 0.f;
                ov[e] = f2bs(v);
            }
            *(bf16x8*)(A2s + SWZ128(s * 16)) = ov;
        }
        __syncthreads();

        // layer 3 (swapped operands): wave owns channels 16w..16w+15
        {
            f32x4 acc3[8] = {};
#pragma unroll
            for (int ks = 0; ks < 2; ++ks) {
                bf16x8 wf = *(bf16x8*)(W3s + SWZ128(((16 * w + lr) * 64 + ks * 32 + lg * 8) * 2));
#pragma unroll
                for (int j = 0; j < 8; ++j) {
                    bf16x8 a2 = *(bf16x8*)(A2s + SWZ128(((16 * j + lr) * 64 + ks * 32 + lg * 8) * 2));
                    acc3[j] = __builtin_amdgcn_mfma_f32_16x16x32_bf16(wf, a2, acc3[j], 0, 0, 0);
                }
            }
            // bn3+relu -> F3: packed 4-channel b64 write per j (row = 16j+lr)
#pragma unroll
            for (int j = 0; j < 8; ++j) {
                s16x4 pk;
#pragma unroll
                for (int r = 0; r < 4; ++r) {
                    float v = fmaf(acc3[j][r], sc3[r], sh3[r]);
                    v = v > 0.f ? v : 0.f;
                    pk[r] = f2bs(v);
                }
                *(s16x4*)(F3s + SWZ256(((16 * j + lr) * 128 + 16 * w + 4 * lg) * 2)) = pk;
            }
        }
        __syncthreads();

        // layer 4: rows 16w..16w+15 per wave; B-frags from LDS W4s
        f32x4 acc4[16] = {};
#pragma unroll
        for (int ks = 0; ks < 4; ++ks) {
            bf16x8 a = *(bf16x8*)(F3s + SWZ256(((16 * w + lr) * 128 + ks * 32 + lg * 8) * 2));
#pragma unroll
            for (int j = 0; j < 16; ++j) {
                bf16x8 b = *(bf16x8*)(W4s + SWZ256(((16 * j + lr) * 128 + ks * 32 + lg * 8) * 2));
                acc4[j] = __builtin_amdgcn_mfma_f32_16x16x32_bf16(a, b, acc4[j], 0, 0, 0);
            }
        }

        // h4pre stats + raw per-wave max (channel c = 16j+lr)
#pragma unroll
        for (int j = 0; j < 16; ++j) {
            int c = 16 * j + lr;
            float s = acc4[j][0] + acc4[j][1] + acc4[j][2] + acc4[j][3];
            float q = acc4[j][0] * acc4[j][0] + acc4[j][1] * acc4[j][1] +
                      acc4[j][2] * acc4[j][2] + acc4[j][3] * acc4[j][3];
            float m = fmaxf(fmaxf(acc4[j][0], acc4[j][1]), fmaxf(acc4[j][2], acc4[j][3]));
            s += __shfl_xor(s, 16); s += __shfl_xor(s, 32);
            q += __shfl_xor(q, 16); q += __shfl_xor(q, 32);
            m = fmaxf(m, __shfl_xor(m, 16));
            m = fmaxf(m, __shfl_xor(m, 32));
            if (lg == 0) {
                atomicAdd(&epiS[c * 2], s);
                atomicAdd(&epiS[c * 2 + 1], q);
                epiM[w * 256 + c] = m;      // plain store: unique (w,c) writer
            }
        }
        // x3 from F3 (post-relu bf16; still valid until end-of-chunk barrier)
        {
            long long pt0 = row0 >> 5;
            int p = tid >> 7, c = tid & 127;
            float m = 0.f;
            for (int r = 0; r < 32; ++r)
                m = fmaxf(m, b2f(*(bf16*)(F3s + SWZ256(((p * 32 + r) * 128 + c) * 2))));
            cat[(pt0 + p) * 512 + 128 + c] = f2b(m);
        }
        __syncthreads();   // epiM ready; F3/A2 reads complete

        // pair-reduce epiM (2 waves per point) -> raw m4
        {
            long long pt0 = row0 >> 5;
            for (int e = tid; e < 1024; e += 512) {
                int p = e >> 8, c = e & 255;
                float m = fmaxf(epiM[(2 * p) * 256 + c], epiM[(2 * p + 1) * 256 + c]);
                m4[(pt0 + p) * 256 + c] = m;
            }
        }
        __syncthreads();   // epiM reads done before next chunk overwrites
    }
    atomicAdd(&sums[g * 1024 + (tid & 511)], tid < 512 ? epiS[tid] : 0.f);
}

// ----------------------- x4 finalize: relu(bn4(m4)) -> cat[256..512] ------
__global__ __launch_bounds__(256) void x4_finalize(const float* __restrict__ m4,
                                                   const float* __restrict__ p4,
                                                   bf16* __restrict__ cat) {
    int row = blockIdx.x;          // g*BNr + pt
    int c = threadIdx.x;
    int g = row / BNr;
    float v = fmaf(m4[(size_t)row * 256 + c], p4[(g * 512 + c) * 2], p4[(g * 512 + c) * 2 + 1]);
    v = v > 0.f ? v : 0.f;
    cat[(size_t)row * 512 + 256 + c] = f2b(v);
}

// ----------------------------------------------------- generic MFMA GEMM --
// BNA=1: bn(pba)+relu on A during staging + x2 maxes -> cat (blockIdx.y==0).
// MODE 0: store f32. MODE 1: stats only. MODE 3: store f32 AND stats.
template <int MODE, int CH, int BNA>
__global__ __launch_bounds__(256, 4) void mfma_gemm(
    const bf16* __restrict__ A, const bf16* __restrict__ Wt,
    float* __restrict__ OutF, bf16* __restrict__ OutB,
    int Cin, int ldOut, long long sA, long long sW, long long sO,
    int rowsPerGroup, const float* __restrict__ params, float* __restrict__ sums,
    const float* __restrict__ pba, bf16* __restrict__ cat) {
    __shared__ char As[16384];   // [128][64] bf16 swz128
    __shared__ char Bs[8192];    // [64][64] bf16 swz128
    __shared__ float epi[128];
    __shared__ float PBs[128];
    __shared__ int x2m[256];     // [4 pts][64 ch]
    int tid = threadIdx.x;
    int w = tid >> 6, l = tid & 63, lg = l >> 4, lr = l & 15;
    int bz = blockIdx.z;
    const bf16* Ap = A + (long long)bz * sA;
    const bf16* Wp = Wt + (long long)bz * sW;
    int o0 = blockIdx.y * 64;
    long long rowB0 = (long long)blockIdx.x * (128 * CH);
    int g = (int)(rowB0 / rowsPerGroup);
    if ((MODE == 1 || MODE == 3) && tid < 128) epi[tid] = 0.f;
    if (BNA && tid < 128) PBs[tid] = pba[g * 1024 + tid];
    int wr = (w >> 1) * 64, wc = (w & 1) * 32;

    for (int ch = 0; ch < CH; ++ch) {
        long long row0 = rowB0 + (long long)ch * 128;
        if (BNA) {
            __syncthreads();
            if (tid < 256) x2m[tid] = 0;
        }
        f32x4 acc[4][2] = {};
        for (int k0 = 0; k0 < Cin; k0 += 64) {
            __syncthreads();
            for (int s = tid; s < 1024; s += 256) {
                if (BNA) {
                    bf16x8 rv = *(const bf16x8*)(Ap + (row0 + (s >> 3)) * Cin + k0 + (s & 7) * 8);
                    int cb = k0 + (s & 7) * 8;
                    int pt = (s >> 3) >> 5;
                    bf16x8 ov;
#pragma unroll
                    for (int e = 0; e < 8; ++e) {
                        float v = fmaf(bs2f(rv[e]), PBs[(cb + e) * 2], PBs[(cb + e) * 2 + 1]);
                        v = v > 0.f ? v : 0.f;
                        ov[e] = f2bs(v);
                        atomicMax(&x2m[pt * 64 + cb + e], __float_as_int(v));
                    }
                    *(bf16x8*)(As + SWZ128(s * 16)) = ov;
                } else {
                    *(bf16x8*)(As + SWZ128(s * 16)) =
                        *(const bf16x8*)(Ap + (row0 + (s >> 3)) * Cin + k0 + (s & 7) * 8);
                }
            }
            for (int s = tid; s < 512; s += 256)
                *(bf16x8*)(Bs + SWZ128(s * 16)) =
                    *(const bf16x8*)(Wp + (long long)(o0 + (s >> 3)) * Cin + k0 + (s & 7) * 8);
            __syncthreads();
#pragma unroll
            for (int ks = 0; ks < 2; ++ks) {
                bf16x8 b0 = *(bf16x8*)(Bs + SWZ128(((wc + lr) * 64 + ks * 32 + lg * 8) * 2));
                bf16x8 b1 = *(bf16x8*)(Bs + SWZ128(((wc + 16 + lr) * 64 + ks * 32 + lg * 8) * 2));
#pragma unroll
                for (int i = 0; i < 4; ++i) {
                    bf16x8 a = *(bf16x8*)(As + SWZ128(((wr + 16 * i + lr) * 64 + ks * 32 + lg * 8) * 2));
                    acc[i][0] = __builtin_amdgcn_mfma_f32_16x16x32_bf16(a, b0, acc[i][0], 0, 0, 0);
                    acc[i][1] = __builtin_amdgcn_mfma_f32_16x16x32_bf16(a, b1, acc[i][1], 0, 0, 0);
                }
            }
        }
        if (BNA && blockIdx.y == 0) {
            long long pt0 = row0 >> 5;
            if (tid < 256) {
                int p = tid >> 6, c = tid & 63;
                cat[(pt0 + p) * 512 + 64 + c] = f2b(__int_as_float(x2m[tid]));
            }
        }
        if (MODE == 1 || MODE == 3) {
#pragma unroll
            for (int j = 0; j < 2; ++j) {
                int c = wc + 16 * j + lr;
                float s = 0.f, q = 0.f;
#pragma unroll
                for (int i = 0; i < 4; ++i)
#pragma unroll
                    for (int r = 0; r < 4; ++r) {
                        float v = acc[i][j][r];
                        s += v; q += v * v;
                    }
                s += __shfl_xor(s, 16); s += __shfl_xor(s, 32);
                q += __shfl_xor(q, 16); q += __shfl_xor(q, 32);
                if (lg == 0) {
                    atomicAdd(&epi[c * 2], s);
                    atomicAdd(&epi[c * 2 + 1], q);
                }
            }
        }
        if (MODE == 0 || MODE == 3) {
            float* Op = OutF + (long long)bz * sO;
#pragma unroll
            for (int j = 0; j < 2; ++j) {
                int gc = o0 + wc + 16 * j + lr;
#pragma unroll
                for (int i = 0; i < 4; ++i)
#pragma unroll
                    for (int r = 0; r < 4; ++r) {
                        long long gr = row0 + wr + 16 * i + 4 * lg + r;
                        Op[gr * ldOut + gc] = acc[i][j][r];
                    }
            }
        }
    }
    if (MODE == 1 || MODE == 3) {
        __syncthreads();
        if (tid < 128) atomicAdd(&sums[g * 1024 + o0 * 2 + tid], epi[tid]);
    }
}

// --------------------------------- l5 finalize: bn+relu -> embB + norms ---
__global__ __launch_bounds__(256) void emb_finalize(const float* __restrict__ h5,
                                                    const float* __restrict__ p5,
                                                    bf16* __restrict__ embB,
                                                    float* __restrict__ nrm) {
    __shared__ float red[256];
    int row = blockIdx.x; int t = threadIdx.x;
    int g = row / BNr;
    float s = 0.f;
#pragma unroll
    for (int i = 0; i < 2; ++i) {
        int c = t + i * 256;
        float v = fmaf(h5[(size_t)row * 512 + c], p5[(g * 512 + c) * 2], p5[(g * 512 + c) * 2 + 1]);
        v = v > 0.f ? v : 0.f;
        bf16 bb = f2b(v);
        embB[(size_t)row * 512 + c] = bb;
        float vb = b2f(bb);
        s += vb * vb;
    }
    red[t] = s; __syncthreads();
    for (int st = 128; st > 0; st >>= 1) { if (t < st) red[t] += red[t + st]; __syncthreads(); }
    if (t == 0) nrm[row] = red[0];
}

// -------------------------------- distance + softmax + weighted sum -------
__global__ __launch_bounds__(256) void corr_kernel(const float* __restrict__ inner,
                                                   const float* __restrict__ nrm,
                                                   const float* __restrict__ tgt,
                                                   float* __restrict__ out) {
    __shared__ float red[256];
    int blk = blockIdx.x;                 // b*N + n
    int b = blk >> 11, n = blk & (NN - 1);
    int t = threadIdx.x;
    const float* inr = inner + ((size_t)b * NN + n) * NN;
    float xx = nrm[b * NN + n];
    float dloc[8];
    float vmax = -INFINITY;
#pragma unroll
    for (int i = 0; i < 8; ++i) {
        int m = t + i * 256;
        float pd = (xx - 2.f * inr[m]) + nrm[BNr + b * NN + m];
        float d = pd > 0.f ? sqrtf(pd) : 0.f;
        dloc[i] = d;
        vmax = fmaxf(vmax, -d);
    }
    red[t] = vmax; __syncthreads();
    for (int s = 128; s > 0; s >>= 1) { if (t < s) red[t] = fmaxf(red[t], red[t + s]); __syncthreads(); }
    vmax = red[0]; __syncthreads();
    const float* tp = tgt + (size_t)b * 3 * NN;
    float se = 0.f, s0 = 0.f, s1 = 0.f, s2 = 0.f;
#pragma unroll
    for (int i = 0; i < 8; ++i) {
        int m = t + i * 256;
        float p = expf(-dloc[i] - vmax);
        se += p;
        s0 += p * tp[m]; s1 += p * tp[NN + m]; s2 += p * tp[2 * NN + m];
    }
    red[t] = se; __syncthreads();
    for (int s = 128; s > 0; s >>= 1) { if (t < s) red[t] += red[t + s]; __syncthreads(); }
    float tot = red[0]; __syncthreads();
    red[t] = s0; __syncthreads();
    for (int s = 128; s > 0; s >>= 1) { if (t < s) red[t] += red[t + s]; __syncthreads(); }
    float o0v = red[0]; __syncthreads();
    red[t] = s1; __syncthreads();
    for (int s = 128; s > 0; s >>= 1) { if (t < s) red[t] += red[t + s]; __syncthreads(); }
    float o1v = red[0]; __syncthreads();
    red[t] = s2; __syncthreads();
    for (int s = 128; s > 0; s >>= 1) { if (t < s) red[t] += red[t + s]; __syncthreads(); }
    float o2v = red[0];
    if (t == 0) {
        out[(size_t)b * 3 * NN + n]          = o0v / tot;
        out[(size_t)b * 3 * NN + NN + n]     = o1v / tot;
        out[(size_t)b * 3 * NN + 2 * NN + n] = o2v / tot;
    }
}

// ------------------------------------------------------------- driver -----
extern "C" void kernel_launch(void* const* d_in, const int* in_sizes, int n_in,
                              void* d_out, int out_size, void* d_ws, size_t ws_size,
                              hipStream_t stream) {
    const float* src = (const float*)d_in[0];
    const float* tgt = (const float*)d_in[1];
    const float* w1  = (const float*)d_in[2];
    const float* w2  = (const float*)d_in[3];
    const float* w3  = (const float*)d_in[4];
    const float* w4  = (const float*)d_in[5];
    const float* w5  = (const float*)d_in[6];
    const float* g1  = (const float*)d_in[7];
    const float* g2  = (const float*)d_in[8];
    const float* g3  = (const float*)d_in[9];
    const float* g4  = (const float*)d_in[10];
    const float* g5  = (const float*)d_in[11];
    const float* b1  = (const float*)d_in[12];
    const float* b2  = (const float*)d_in[13];
    const float* b3  = (const float*)d_in[14];
    const float* b4  = (const float*)d_in[15];
    const float* b5  = (const float*)d_in[16];
    float* out = (float*)d_out;
    char* ws = (char*)d_ws;
    (void)in_sizes; (void)n_in;

    size_t off = 0;
    auto alloc = [&](size_t bytes) { size_t o = off; off = (off + bytes + 255) & ~(size_t)255; return o; };
    int*   idx    = (int*)(ws + alloc((size_t)SR * 4));                 // 2 MB
    bf16*  H2     = (bf16*)(ws + alloc((size_t)SR * 64 * 2));           // 64 MB (overlay inner f32)
    bf16*  cat    = (bf16*)(ws + alloc((size_t)GG * BNr * 512 * 2));    // 16 MB
    bf16*  embB   = (bf16*)(ws + alloc((size_t)GG * BNr * 512 * 2));    // 16 MB
    float* h5     = (float*)(ws + alloc((size_t)GG * BNr * 512 * 4));   // 33.5 MB
    float* m4     = (float*)(ws + alloc((size_t)GG * BNr * 256 * 4));   // 16.8 MB
    float* nrm    = (float*)(ws + alloc((size_t)GG * BNr * 4));
    float* sums   = (float*)(ws + alloc(2048 * 4));
    float* g1s    = (float*)(ws + alloc(64 * 4));
    float* g1part = (float*)(ws + alloc((size_t)GG * 2048 * 32 * 4));   // 512 KB
    float* prm    = (float*)(ws + alloc(5 * 2048 * 4));
    bf16*  w2b    = (bf16*)(ws + alloc(4096 * 2));
    bf16*  w3b    = (bf16*)(ws + alloc(8192 * 2));
    bf16*  w4b    = (bf16*)(ws + alloc(32768 * 2));
    bf16*  w5b    = (bf16*)(ws + alloc(262144 * 2));
    float* P1 = prm, *P2 = prm + 2048, *P3 = prm + 4096, *P4 = prm + 6144, *P5 = prm + 8192;
    float* inner = (float*)H2;   // overlay: SR*64*2 bytes == B*N*N*4 bytes exactly

    if (ws_size < off) {
        hipMemsetAsync(d_out, 0, (size_t)out_size * 4, stream);
        return;
    }

    zero_kernel<<<8, 256, 0, stream>>>(sums, 2048);   // first-call poison guard
    knn_kernel<<<GG * BB * NN / 4, 256, 0, stream>>>(src, tgt, idx, g1part);
    cvt_all_kernel<<<1024, 256, 0, stream>>>(w2, w3, w4, w5, w2b, w3b, w4b, w5b);

    // layer-1 BN params: reduce knn's Gram partials, then finalize
    reduce_g1_kernel<<<GG * 27, 256, 0, stream>>>(g1part, g1s);
    finalize_l1_kernel<<<1, 128, 0, stream>>>(g1s, w1, g1, b1, (float)SGr, P1);

    // apply pass: F1+x1, l2 -> raw h2pre (H2) + h2 stats
    l12_mfma<<<SR / 256, 256, 0, stream>>>(src, tgt, w1, w2b, idx, P1, H2, cat, sums);
    finalize_bn_kernel<<<1, 128, 0, stream>>>(sums, 64, g2, b2, (float)SGr, P2);

    // layer 3 stats (bn2-on-load of raw H2) + x2 -> cat
    mfma_gemm<1, 4, 1><<<dim3(SR / 512, 2, 1), 256, 0, stream>>>(
        H2, w3b, nullptr, nullptr, 64, 0, 0, 0, 0, SGr, nullptr, sums, P2, cat);
    finalize_bn_kernel<<<2, 128, 0, stream>>>(sums, 128, g3, b3, (float)SGr, P3);

    // layers 3+4 chain: SINGLE pass (h4 stats + x3 + raw m4)
    chain34_mfma<<<1024, 512, 142848, stream>>>(H2, w3b, w4b, P2, P3, cat, sums, m4);
    finalize_bn_kernel<<<4, 128, 0, stream>>>(sums, 256, g4, b4, (float)SGr, P4);
    x4_finalize<<<GG * BNr, 256, 0, stream>>>(m4, P4, cat);

    // layer 5: single GEMM pass (raw h5 f32 + stats), then fused finalize
    mfma_gemm<3, 1, 0><<<dim3(GG * BNr / 128, 8, 1), 256, 0, stream>>>(
        cat, w5b, h5, nullptr, 512, 512, 0, 0, 0, BNr, nullptr, sums, nullptr, nullptr);
    finalize_bn_kernel<<<8, 128, 0, stream>>>(sums, 512, g5, b5, (float)BNr, P5);
    emb_finalize<<<GG * BNr, 256, 0, stream>>>(h5, P5, embB, nrm);

    // inner products: per-batch embB_src x embB_tgt^T -> inner (overlay on H2)
    mfma_gemm<0, 1, 0><<<dim3(NN / 128, NN / 64, BB), 256, 0, stream>>>(
        embB, embB + (size_t)BNr * 512, inner, nullptr, 512, 2048,
        (long long)NN * 512, (long long)NN * 512, (long long)NN * NN,
        SGr, nullptr, nullptr, nullptr, nullptr);

    // distance + softmax + weighted sum of tgt points
    corr_kernel<<<BB * NN, 256, 0, stream>>>(inner, nrm, tgt, out);
}

// Round 21
// 590.599 us; speedup vs baseline: 1.0314x; 1.0074x over previous
//
#include <hip/hip_runtime.h>
#include <hip/hip_bf16.h>
#include <math.h>

#define BB 4
#define NN 2048
#define KK 32
#define GG 2
constexpr int BNr = BB * NN;       // 8192 point-rows per group
constexpr int SGr = BB * NN * KK;  // 262144 sample rows per group
constexpr int SR  = GG * SGr;      // 524288 total sample rows

typedef __hip_bfloat16 bf16;
typedef __attribute__((ext_vector_type(8))) short bf16x8;
typedef __attribute__((ext_vector_type(4))) short s16x4;
typedef __attribute__((ext_vector_type(4))) float f32x4;
__device__ __forceinline__ float b2f(bf16 v) { return __bfloat162float(v); }
__device__ __forceinline__ bf16  f2b(float v) { return __float2bfloat16(v); }
__device__ __forceinline__ short f2bs(float v) { bf16 b = f2b(v); return *(short*)&b; }
__device__ __forceinline__ float bs2f(short s) { bf16 b; *(short*)&b = s; return b2f(b); }

// XOR swizzles for LDS tiles (byte-offset based; row = stride 128B / 256B)
#define SWZ128(b) ((b) ^ ((((b) >> 7) & 7) << 4))
#define SWZ256(b) ((b) ^ ((((b) >> 8) & 7) << 4))

// ------------------------------------------------- kNN (wave-per-query) ---
// + fused layer-1 feature Gram -> per-block partials (no global atomics).
__global__ __launch_bounds__(256) void knn_kernel(const float* __restrict__ src,
                                                  const float* __restrict__ tgt,
                                                  int* __restrict__ idx_out,
                                                  float* __restrict__ g1part) {
    __shared__ float pts[3 * NN];   // 24 KB
    __shared__ float xxs[NN];       // 8 KB
    __shared__ int   sel[4][32];
    __shared__ float Gs[27];
    int blk = blockIdx.x;           // (g*B+b)*(NN/4) + chunk
    int gb = blk >> 9;              // / (NN/4)
    int chunk = blk & 511;
    int g = gb >> 2, b = gb & 3;
    const float* x = (g == 0 ? src : tgt) + (size_t)b * 3 * NN;
    int t = threadIdx.x;
    if (t < 27) Gs[t] = 0.f;
    for (int i = t; i < 3 * NN; i += 256) pts[i] = x[i];
    __syncthreads();
    for (int m = t; m < NN; m += 256) {
        float p0 = pts[m], p1 = pts[NN + m], p2 = pts[2 * NN + m];
        xxs[m] = p0 * p0 + p1 * p1 + p2 * p2;
    }
    __syncthreads();
    int w = t >> 6, l = t & 63;
    int n = chunk * 4 + w;
    float q0 = pts[n], q1 = pts[NN + n], q2 = pts[2 * NN + n];
    float xxn = xxs[n];
    float d2[32];
#pragma unroll
    for (int s = 0; s < 32; ++s) {
        int m = s * 64 + l;
        float dot = q0 * pts[m] + q1 * pts[NN + m] + q2 * pts[2 * NN + m];
        d2[s] = (xxn - 2.0f * dot) + xxs[m];
    }
    // cached group minima (4 groups x 8 slots)
    float gval[4]; int gslot[4];
#pragma unroll
    for (int G = 0; G < 4; ++G) {
        float v = d2[G * 8]; int sl = G * 8;
#pragma unroll
        for (int s = 1; s < 8; ++s)
            if (d2[G * 8 + s] < v) { v = d2[G * 8 + s]; sl = G * 8 + s; }
        gval[G] = v; gslot[G] = sl;
    }
    int* outp = idx_out + ((size_t)gb * NN + n) * KK;
    for (int k = 0; k < KK; ++k) {
        float bv = fminf(fminf(gval[0], gval[1]), fminf(gval[2], gval[3]));
        float gv = bv;
#pragma unroll
        for (int off = 1; off < 64; off <<= 1) gv = fminf(gv, __shfl_xor(gv, off));
        unsigned long long mask = __ballot(bv == gv);
        int winner = (int)__builtin_ctzll(mask);
        if (l == winner) {
            int grp = (gval[0] == gv) ? 0 : (gval[1] == gv) ? 1 : (gval[2] == gv) ? 2 : 3;
#pragma unroll
            for (int G = 0; G < 4; ++G)
                if (G == grp) {
                    int bs = gslot[G];
                    outp[k] = bs * 64 + l;
                    sel[w][k] = bs * 64 + l;
#pragma unroll
                    for (int s = 0; s < 8; ++s)
                        if (G * 8 + s == bs) d2[G * 8 + s] = INFINITY;
                    float v = d2[G * 8]; int sl = G * 8;
#pragma unroll
                    for (int s = 1; s < 8; ++s)
                        if (d2[G * 8 + s] < v) { v = d2[G * 8 + s]; sl = G * 8 + s; }
                    gval[G] = v; gslot[G] = sl;
                }
        }
    }
    __syncthreads();   // sel visible across lanes
    // feature Gram accumulation (layer-1 BN stats)
    float nx = 0.f, ny = 0.f, nz = 0.f;
    if (l < 32) {
        int m = sel[w][l];
        nx = pts[m]; ny = pts[NN + m]; nz = pts[2 * NN + m];
    }
    float v9[9] = {nx * nx, nx * ny, nx * nz, ny * ny, ny * nz, nz * nz, nx, ny, nz};
#pragma unroll
    for (int e = 0; e < 9; ++e) {
#pragma unroll
        for (int off = 1; off < 64; off <<= 1) v9[e] += __shfl_xor(v9[e], off);
    }
    if (l == 0) {
        float c3[3] = {q0, q1, q2};
#pragma unroll
        for (int e = 0; e < 6; ++e) atomicAdd(&Gs[e], v9[e]);
#pragma unroll
        for (int a = 0; a < 3; ++a)
#pragma unroll
            for (int bb = 0; bb < 3; ++bb)
                atomicAdd(&Gs[6 + a * 3 + bb], v9[6 + a] * c3[bb]);
        atomicAdd(&Gs[15], 32.f * q0 * q0);
        atomicAdd(&Gs[16], 32.f * q0 * q1);
        atomicAdd(&Gs[17], 32.f * q0 * q2);
        atomicAdd(&Gs[18], 32.f * q1 * q1);
        atomicAdd(&Gs[19], 32.f * q1 * q2);
        atomicAdd(&Gs[20], 32.f * q2 * q2);
        atomicAdd(&Gs[21], v9[6]);
        atomicAdd(&Gs[22], v9[7]);
        atomicAdd(&Gs[23], v9[8]);
        atomicAdd(&Gs[24], 32.f * q0);
        atomicAdd(&Gs[25], 32.f * q1);
        atomicAdd(&Gs[26], 32.f * q2);
    }
    __syncthreads();
    if (t < 27) g1part[(size_t)blk * 32 + t] = Gs[t];   // plain store, no atomics
}

// reduce per-block Gram partials: 54 blocks, one (g,e) each
__global__ __launch_bounds__(256) void reduce_g1_kernel(const float* __restrict__ part,
                                                        float* __restrict__ g1s) {
    __shared__ float red[256];
    int bx = blockIdx.x;
    int g = bx / 27, e = bx - g * 27;
    int t = threadIdx.x;
    float s = 0.f;
    for (int b = t; b < 2048; b += 256) s += part[((size_t)g * 2048 + b) * 32 + e];
    red[t] = s; __syncthreads();
    for (int st = 128; st > 0; st >>= 1) { if (t < st) red[t] += red[t + st]; __syncthreads(); }
    if (t == 0) g1s[g * 27 + e] = red[0];
}

// ---------------------------------------------------------------- misc ----
__global__ void zero_kernel(float* __restrict__ p, int n) {
    int i = blockIdx.x * 256 + threadIdx.x;
    if (i < n) p[i] = 0.f;
}

__global__ void cvt_all_kernel(const float* __restrict__ w2, const float* __restrict__ w3,
                               const float* __restrict__ w4, const float* __restrict__ w5,
                               bf16* __restrict__ w2b, bf16* __restrict__ w3b,
                               bf16* __restrict__ w4b, bf16* __restrict__ w5b) {
    int i = blockIdx.x * 256 + threadIdx.x;
    if (i < 4096)   w2b[i] = f2b(w2[i]);
    if (i < 8192)   w3b[i] = f2b(w3[i]);
    if (i < 32768)  w4b[i] = f2b(w4[i]);
    if (i < 262144) w5b[i] = f2b(w5[i]);
}

// finalize: compute scale/shift and zero the consumed sums for the next stage
__global__ void finalize_bn_kernel(float* __restrict__ sums, int C,
                                   const float* __restrict__ gamma,
                                   const float* __restrict__ beta,
                                   float cnt, float* __restrict__ params) {
    int i = blockIdx.x * blockDim.x + threadIdx.x;
    if (i >= GG * C) return;
    int g = i / C, c = i - g * C;
    float s  = sums[(g * 512 + c) * 2 + 0];
    float sq = sums[(g * 512 + c) * 2 + 1];
    float mean = s / cnt;
    float var = sq / cnt - mean * mean;
    if (var < 0.f) var = 0.f;
    float sc = gamma[c] * rsqrtf(var + 1e-5f);
    params[(g * 512 + c) * 2 + 0] = sc;
    params[(g * 512 + c) * 2 + 1] = beta[c] - mean * sc;
    sums[(g * 512 + c) * 2 + 0] = 0.f;
    sums[(g * 512 + c) * 2 + 1] = 0.f;
}

// layer-1 BN params from feature Gram: s = w.fsum, q = w^T G w
__global__ void finalize_l1_kernel(const float* __restrict__ g1s,
                                   const float* __restrict__ w1,
                                   const float* __restrict__ gamma,
                                   const float* __restrict__ beta,
                                   float cnt, float* __restrict__ params) {
    int i = blockIdx.x * blockDim.x + threadIdx.x;
    if (i >= GG * 64) return;
    int g = i >> 6, o = i & 63;
    const float* G = g1s + g * 27;
    float wv[6];
#pragma unroll
    for (int c = 0; c < 6; ++c) wv[c] = w1[o * 6 + c];
    float s = wv[0] * G[21] + wv[1] * G[22] + wv[2] * G[23] +
              wv[3] * G[24] + wv[4] * G[25] + wv[5] * G[26];
    const int UT[6][6] = {{0, 1, 2, 6, 7, 8},   {1, 3, 4, 9, 10, 11},
                          {2, 4, 5, 12, 13, 14},{6, 9, 12, 15, 16, 17},
                          {7, 10, 13, 16, 18, 19},{8, 11, 14, 17, 19, 20}};
    float q = 0.f;
#pragma unroll
    for (int a = 0; a < 6; ++a)
#pragma unroll
        for (int bb = 0; bb < 6; ++bb) q += wv[a] * wv[bb] * G[UT[a][bb]];
    float mean = s / cnt;
    float var = q / cnt - mean * mean;
    if (var < 0.f) var = 0.f;
    float sc = gamma[o] * rsqrtf(var + 1e-5f);
    params[(g * 512 + o) * 2 + 0] = sc;
    params[(g * 512 + o) * 2 + 1] = beta[o] - mean * sc;
}

// ----------------------------------------------- MFMA layers 1+2 ----------
// Apply pass only: gather -> l1 MFMA -> bn1+relu -> F1 (LDS) + x1 -> cat,
// l2 MFMA -> store RAW h2pre -> H2, accumulate h2pre stats -> sums.
__global__ __launch_bounds__(256, 3) void l12_mfma(
    const float* __restrict__ src, const float* __restrict__ tgt,
    const float* __restrict__ w1, const bf16* __restrict__ w2b,
    const int* __restrict__ idx, const float* __restrict__ p1,
    bf16* __restrict__ H2, bf16* __restrict__ cat, float* __restrict__ sums) {
    __shared__ char F1s[32768];    // [256][64] bf16 swz128
    __shared__ char W2s[8192];     // [64][64] bf16 swz128
    __shared__ float epiA[512];    // x1 int-max [8][64]
    __shared__ float epiB[128];    // h2 stats [64][2]
    int tid = threadIdx.x;
    int w = tid >> 6, l = tid & 63, lg = l >> 4, lr = l & 15;
    long long row0 = (long long)blockIdx.x * 256;
    int g = (int)(row0 / SGr);

    epiA[tid] = 0.f; epiA[tid + 256] = 0.f;
    if (tid < 128) epiB[tid] = 0.f;
    for (int s = tid; s < 512; s += 256)
        *(bf16x8*)(W2s + SWZ128(s * 16)) = *(const bf16x8*)(w2b + s * 8);

    bf16x8 af[4];
#pragma unroll
    for (int i = 0; i < 4; ++i) {
        af[i] = (bf16x8){0, 0, 0, 0, 0, 0, 0, 0};
        if (lg == 0) {
            int rr = (int)row0 + w * 64 + 16 * i + lr;
            int nrow = rr >> 5;
            int n = nrow & (NN - 1);
            int gb = nrow >> 11;
            int b = gb & 3, gg = gb >> 2;
            const float* x = (gg ? tgt : src) + (size_t)b * 3 * NN;
            int j = idx[rr];
            af[i][0] = f2bs(x[j]);
            af[i][1] = f2bs(x[NN + j]);
            af[i][2] = f2bs(x[2 * NN + j]);
            af[i][3] = f2bs(x[n]);
            af[i][4] = f2bs(x[NN + n]);
            af[i][5] = f2bs(x[2 * NN + n]);
        }
    }
    bf16x8 bf1[4];
#pragma unroll
    for (int j = 0; j < 4; ++j) {
        bf1[j] = (bf16x8){0, 0, 0, 0, 0, 0, 0, 0};
        if (lg == 0) {
            int o = 16 * j + lr;
#pragma unroll
            for (int c = 0; c < 6; ++c) bf1[j][c] = f2bs(w1[o * 6 + c]);
        }
    }

    f32x4 acc1[4][4] = {};
#pragma unroll
    for (int i = 0; i < 4; ++i)
#pragma unroll
        for (int j = 0; j < 4; ++j)
            acc1[i][j] = __builtin_amdgcn_mfma_f32_16x16x32_bf16(af[i], bf1[j], acc1[i][j], 0, 0, 0);

    __syncthreads();

    // bn1 + relu -> F1 (bf16) + x1 max
#pragma unroll
    for (int j = 0; j < 4; ++j) {
        int c = 16 * j + lr;
        float sc = p1[(g * 512 + c) * 2], sh = p1[(g * 512 + c) * 2 + 1];
#pragma unroll
        for (int i = 0; i < 4; ++i) {
            float m = 0.f;
#pragma unroll
            for (int r = 0; r < 4; ++r) {
                float v = fmaf(acc1[i][j][r], sc, sh);
                v = v > 0.f ? v : 0.f;
                m = fmaxf(m, v);
                int rowi = w * 64 + 16 * i + 4 * lg + r;
                *(bf16*)(F1s + SWZ128((rowi * 64 + c) * 2)) = f2b(v);
            }
            int p = 2 * w + (i >> 1);
            atomicMax((int*)epiA + p * 64 + c, __float_as_int(m));
        }
    }
    __syncthreads();

    {
        long long pt0 = row0 >> 5;
        for (int e = tid; e < 512; e += 256) {
            int p = e >> 6, c = e & 63;
            cat[(pt0 + p) * 512 + c] = f2b(__int_as_float(((int*)epiA)[p * 64 + c]));
        }
    }

    // layer 2 MFMA: F1 @ w2^T
    f32x4 acc2[4][4] = {};
#pragma unroll
    for (int ks = 0; ks < 2; ++ks) {
        bf16x8 bv[4];
#pragma unroll
        for (int j = 0; j < 4; ++j)
            bv[j] = *(bf16x8*)(W2s + SWZ128(((16 * j + lr) * 64 + ks * 32 + lg * 8) * 2));
#pragma unroll
        for (int i = 0; i < 4; ++i) {
            bf16x8 a = *(bf16x8*)(F1s + SWZ128(((w * 64 + 16 * i + lr) * 64 + ks * 32 + lg * 8) * 2));
#pragma unroll
            for (int j = 0; j < 4; ++j)
                acc2[i][j] = __builtin_amdgcn_mfma_f32_16x16x32_bf16(a, bv[j], acc2[i][j], 0, 0, 0);
        }
    }

    // store RAW h2pre + accumulate h2pre stats
#pragma unroll
    for (int j = 0; j < 4; ++j) {
        int c = 16 * j + lr;
        float s = 0.f, q = 0.f;
#pragma unroll
        for (int i = 0; i < 4; ++i)
#pragma unroll
            for (int r = 0; r < 4; ++r) {
                float v = acc2[i][j][r];
                s += v; q += v * v;
                long long gr = row0 + w * 64 + 16 * i + 4 * lg + r;
                H2[gr * 64 + c] = f2b(v);
            }
        s += __shfl_xor(s, 16); s += __shfl_xor(s, 32);
        q += __shfl_xor(q, 16); q += __shfl_xor(q, 32);
        if (lg == 0) {
            atomicAdd(&epiB[c * 2], s);
            atomicAdd(&epiB[c * 2 + 1], q);
        }
    }
    __syncthreads();
    if (tid < 128) atomicAdd(&sums[g * 1024 + tid], epiB[tid]);
}

// ------------------------------------------- MFMA chain: layers 3+4 -------
// SINGLE pass, 2 barriers/chunk: h4pre stats + x3 (scalar F3 re-read) +
// per-wave x4 half-maxes written DIRECTLY to global m4h[pt][w&1][c]
// (waves 2p,2p+1 own point p) -- no epiM LDS, no pair-reduce barriers.
// max commutes with relu(bn4) since gamma4 = ones > 0.
__global__ __launch_bounds__(512, 2) void chain34_mfma(
    const bf16* __restrict__ H2, const bf16* __restrict__ w3b,
    const bf16* __restrict__ w4b, const float* __restrict__ p2,
    const float* __restrict__ p3, bf16* __restrict__ cat,
    float* __restrict__ sums, float* __restrict__ m4h) {
    extern __shared__ char smem[];
    char* W3s = smem;                       // 16384  [128][64] bf16 swz128
    char* W4s = smem + 16384;               // 65536  [256][128] bf16 swz256
    char* A2s = smem + 81920;               // 16384  [128][64] bf16 swz128
    char* F3s = smem + 98304;               // 32768  [128][128] bf16 swz256
    float* P3s  = (float*)(smem + 131072);  // 1024 B (256 f32)
    float* epiS = (float*)(smem + 132096);  // 2048 B (512 f32) h4 stats
    float* P2s  = (float*)(smem + 134144);  // 512 B (128 f32)

    int tid = threadIdx.x;
    int w = tid >> 6, l = tid & 63, lg = l >> 4, lr = l & 15;
    long long rowB0 = (long long)blockIdx.x * 512;
    int g = (int)(rowB0 / SGr);

    for (int s = tid; s < 1024; s += 512)
        *(bf16x8*)(W3s + SWZ128(s * 16)) = *(const bf16x8*)(w3b + s * 8);
    for (int s = tid; s < 4096; s += 512)
        *(bf16x8*)(W4s + SWZ256(s * 16)) = *(const bf16x8*)(w4b + s * 8);
    if (tid < 256) P3s[tid] = p3[g * 1024 + tid];
    if (tid < 128) P2s[tid] = p2[g * 1024 + tid];
    epiS[tid & 511] = 0.f;
    __syncthreads();

    // bn3 params for this lane's 4 channels (c = 16w + 4lg + r)
    float sc3[4], sh3[4];
#pragma unroll
    for (int r = 0; r < 4; ++r) {
        int c = 16 * w + 4 * lg + r;
        sc3[r] = P3s[c * 2]; sh3[r] = P3s[c * 2 + 1];
    }

    for (int chunk = 0; chunk < 4; ++chunk) {
        long long row0 = rowB0 + chunk * 128;
        for (int s = tid; s < 1024; s += 512) {
            bf16x8 rv = *(const bf16x8*)(H2 + row0 * 64 + s * 8);
            int cb = (s & 7) * 8;
            bf16x8 ov;
#pragma unroll
            for (int e = 0; e < 8; ++e) {
                float v = fmaf(bs2f(rv[e]), P2s[(cb + e) * 2], P2s[(cb + e) * 2 + 1]);
                v = v > 0.f ? v : 0.f;
                ov[e] = f2bs(v);
            }
            *(bf16x8*)(A2s + SWZ128(s * 16)) = ov;
        }
        __syncthreads();   // A2 ready (also guards F3 from previous chunk's readers)

        // layer 3 (swapped operands): wave owns channels 16w..16w+15
        {
            f32x4 acc3[8] = {};
#pragma unroll
            for (int ks = 0; ks < 2; ++ks) {
                bf16x8 wf = *(bf16x8*)(W3s + SWZ128(((16 * w + lr) * 64 + ks * 32 + lg * 8) * 2));
#pragma unroll
                for (int j = 0; j < 8; ++j) {
                    bf16x8 a2 = *(bf16x8*)(A2s + SWZ128(((16 * j + lr) * 64 + ks * 32 + lg * 8) * 2));
                    acc3[j] = __builtin_amdgcn_mfma_f32_16x16x32_bf16(wf, a2, acc3[j], 0, 0, 0);
                }
            }
            // bn3+relu -> F3: packed 4-channel b64 write per j (row = 16j+lr)
#pragma unroll
            for (int j = 0; j < 8; ++j) {
                s16x4 pk;
#pragma unroll
                for (int r = 0; r < 4; ++r) {
                    float v = fmaf(acc3[j][r], sc3[r], sh3[r]);
                    v = v > 0.f ? v : 0.f;
                    pk[r] = f2bs(v);
                }
                *(s16x4*)(F3s + SWZ256(((16 * j + lr) * 128 + 16 * w + 4 * lg) * 2)) = pk;
            }
        }
        __syncthreads();   // F3 ready; A2 reads complete

        // layer 4: rows 16w..16w+15 per wave; B-frags from LDS W4s
        f32x4 acc4[16] = {};
#pragma unroll
        for (int ks = 0; ks < 4; ++ks) {
            bf16x8 a = *(bf16x8*)(F3s + SWZ256(((16 * w + lr) * 128 + ks * 32 + lg * 8) * 2));
#pragma unroll
            for (int j = 0; j < 16; ++j) {
                bf16x8 b = *(bf16x8*)(W4s + SWZ256(((16 * j + lr) * 128 + ks * 32 + lg * 8) * 2));
                acc4[j] = __builtin_amdgcn_mfma_f32_16x16x32_bf16(a, b, acc4[j], 0, 0, 0);
            }
        }

        // h4pre stats + per-wave half-max DIRECT to global (unique writer)
        {
            long long pt = (row0 >> 5) + (w >> 1);   // point owned by this wave pair
#pragma unroll
            for (int j = 0; j < 16; ++j) {
                int c = 16 * j + lr;
                float s = acc4[j][0] + acc4[j][1] + acc4[j][2] + acc4[j][3];
                float q = acc4[j][0] * acc4[j][0] + acc4[j][1] * acc4[j][1] +
                          acc4[j][2] * acc4[j][2] + acc4[j][3] * acc4[j][3];
                float m = fmaxf(fmaxf(acc4[j][0], acc4[j][1]), fmaxf(acc4[j][2], acc4[j][3]));
                s += __shfl_xor(s, 16); s += __shfl_xor(s, 32);
                q += __shfl_xor(q, 16); q += __shfl_xor(q, 32);
                m = fmaxf(m, __shfl_xor(m, 16));
                m = fmaxf(m, __shfl_xor(m, 32));
                if (lg == 0) {
                    atomicAdd(&epiS[c * 2], s);
                    atomicAdd(&epiS[c * 2 + 1], q);
                    m4h[(pt * 2 + (w & 1)) * 256 + c] = m;   // plain global store
                }
            }
        }
        // x3 from F3 (post-relu bf16; next F3 overwrite is after next
        // chunk's staging barrier, so no extra barrier needed here)
        {
            long long pt0 = row0 >> 5;
            int p = tid >> 7, c = tid & 127;
            float m = 0.f;
            for (int r = 0; r < 32; ++r)
                m = fmaxf(m, b2f(*(bf16*)(F3s + SWZ256(((p * 32 + r) * 128 + c) * 2))));
            cat[(pt0 + p) * 512 + 128 + c] = f2b(m);
        }
    }
    __syncthreads();
    atomicAdd(&sums[g * 1024 + (tid & 511)], tid < 512 ? epiS[tid] : 0.f);
}

// ------------- x4 finalize: relu(bn4(max of 2 halves)) -> cat[256..512] ---
__global__ __launch_bounds__(256) void x4_finalize(const float* __restrict__ m4h,
                                                   const float* __restrict__ p4,
                                                   bf16* __restrict__ cat) {
    int row = blockIdx.x;          // g*BNr + pt
    int c = threadIdx.x;
    int g = row / BNr;
    float m = fmaxf(m4h[((size_t)row * 2) * 256 + c], m4h[((size_t)row * 2 + 1) * 256 + c]);
    float v = fmaf(m, p4[(g * 512 + c) * 2], p4[(g * 512 + c) * 2 + 1]);
    v = v > 0.f ? v : 0.f;
    cat[(size_t)row * 512 + 256 + c] = f2b(v);
}

// ----------------------------------------------------- generic MFMA GEMM --
// BNA=1: bn(pba)+relu on A during staging + x2 maxes -> cat (blockIdx.y==0).
// MODE 0: store f32. MODE 1: stats only. MODE 3: store f32 AND stats.
template <int MODE, int CH, int BNA>
__global__ __launch_bounds__(256, 4) void mfma_gemm(
    const bf16* __restrict__ A, const bf16* __restrict__ Wt,
    float* __restrict__ OutF, bf16* __restrict__ OutB,
    int Cin, int ldOut, long long sA, long long sW, long long sO,
    int rowsPerGroup, const float* __restrict__ params, float* __restrict__ sums,
    const float* __restrict__ pba, bf16* __restrict__ cat) {
    __shared__ char As[16384];   // [128][64] bf16 swz128
    __shared__ char Bs[8192];    // [64][64] bf16 swz128
    __shared__ float epi[128];
    __shared__ float PBs[128];
    __shared__ int x2m[256];     // [4 pts][64 ch]
    int tid = threadIdx.x;
    int w = tid >> 6, l = tid & 63, lg = l >> 4, lr = l & 15;
    int bz = blockIdx.z;
    const bf16* Ap = A + (long long)bz * sA;
    const bf16* Wp = Wt + (long long)bz * sW;
    int o0 = blockIdx.y * 64;
    long long rowB0 = (long long)blockIdx.x * (128 * CH);
    int g = (int)(rowB0 / rowsPerGroup);
    if ((MODE == 1 || MODE == 3) && tid < 128) epi[tid] = 0.f;
    if (BNA && tid < 128) PBs[tid] = pba[g * 1024 + tid];
    int wr = (w >> 1) * 64, wc = (w & 1) * 32;

    for (int ch = 0; ch < CH; ++ch) {
        long long row0 = rowB0 + (long long)ch * 128;
        if (BNA) {
            __syncthreads();
            if (tid < 256) x2m[tid] = 0;
        }
        f32x4 acc[4][2] = {};
        for (int k0 = 0; k0 < Cin; k0 += 64) {
            __syncthreads();
            for (int s = tid; s < 1024; s += 256) {
                if (BNA) {
                    bf16x8 rv = *(const bf16x8*)(Ap + (row0 + (s >> 3)) * Cin + k0 + (s & 7) * 8);
                    int cb = k0 + (s & 7) * 8;
                    int pt = (s >> 3) >> 5;
                    bf16x8 ov;
#pragma unroll
                    for (int e = 0; e < 8; ++e) {
                        float v = fmaf(bs2f(rv[e]), PBs[(cb + e) * 2], PBs[(cb + e) * 2 + 1]);
                        v = v > 0.f ? v : 0.f;
                        ov[e] = f2bs(v);
                        atomicMax(&x2m[pt * 64 + cb + e], __float_as_int(v));
                    }
                    *(bf16x8*)(As + SWZ128(s * 16)) = ov;
                } else {
                    *(bf16x8*)(As + SWZ128(s * 16)) =
                        *(const bf16x8*)(Ap + (row0 + (s >> 3)) * Cin + k0 + (s & 7) * 8);
                }
            }
            for (int s = tid; s < 512; s += 256)
                *(bf16x8*)(Bs + SWZ128(s * 16)) =
                    *(const bf16x8*)(Wp + (long long)(o0 + (s >> 3)) * Cin + k0 + (s & 7) * 8);
            __syncthreads();
#pragma unroll
            for (int ks = 0; ks < 2; ++ks) {
                bf16x8 b0 = *(bf16x8*)(Bs + SWZ128(((wc + lr) * 64 + ks * 32 + lg * 8) * 2));
                bf16x8 b1 = *(bf16x8*)(Bs + SWZ128(((wc + 16 + lr) * 64 + ks * 32 + lg * 8) * 2));
#pragma unroll
                for (int i = 0; i < 4; ++i) {
                    bf16x8 a = *(bf16x8*)(As + SWZ128(((wr + 16 * i + lr) * 64 + ks * 32 + lg * 8) * 2));
                    acc[i][0] = __builtin_amdgcn_mfma_f32_16x16x32_bf16(a, b0, acc[i][0], 0, 0, 0);
                    acc[i][1] = __builtin_amdgcn_mfma_f32_16x16x32_bf16(a, b1, acc[i][1], 0, 0, 0);
                }
            }
        }
        if (BNA && blockIdx.y == 0) {
            long long pt0 = row0 >> 5;
            if (tid < 256) {
                int p = tid >> 6, c = tid & 63;
                cat[(pt0 + p) * 512 + 64 + c] = f2b(__int_as_float(x2m[tid]));
            }
        }
        if (MODE == 1 || MODE == 3) {
#pragma unroll
            for (int j = 0; j < 2; ++j) {
                int c = wc + 16 * j + lr;
                float s = 0.f, q = 0.f;
#pragma unroll
                for (int i = 0; i < 4; ++i)
#pragma unroll
                    for (int r = 0; r < 4; ++r) {
                        float v = acc[i][j][r];
                        s += v; q += v * v;
                    }
                s += __shfl_xor(s, 16); s += __shfl_xor(s, 32);
                q += __shfl_xor(q, 16); q += __shfl_xor(q, 32);
                if (lg == 0) {
                    atomicAdd(&epi[c * 2], s);
                    atomicAdd(&epi[c * 2 + 1], q);
                }
            }
        }
        if (MODE == 0 || MODE == 3) {
            float* Op = OutF + (long long)bz * sO;
#pragma unroll
            for (int j = 0; j < 2; ++j) {
                int gc = o0 + wc + 16 * j + lr;
#pragma unroll
                for (int i = 0; i < 4; ++i)
#pragma unroll
                    for (int r = 0; r < 4; ++r) {
                        long long gr = row0 + wr + 16 * i + 4 * lg + r;
                        Op[gr * ldOut + gc] = acc[i][j][r];
                    }
            }
        }
    }
    if (MODE == 1 || MODE == 3) {
        __syncthreads();
        if (tid < 128) atomicAdd(&sums[g * 1024 + o0 * 2 + tid], epi[tid]);
    }
}

// --------------------------------- l5 finalize: bn+relu -> embB + norms ---
__global__ __launch_bounds__(256) void emb_finalize(const float* __restrict__ h5,
                                                    const float* __restrict__ p5,
                                                    bf16* __restrict__ embB,
                                                    float* __restrict__ nrm) {
    __shared__ float red[256];
    int row = blockIdx.x; int t = threadIdx.x;
    int g = row / BNr;
    float s = 0.f;
#pragma unroll
    for (int i = 0; i < 2; ++i) {
        int c = t + i * 256;
        float v = fmaf(h5[(size_t)row * 512 + c], p5[(g * 512 + c) * 2], p5[(g * 512 + c) * 2 + 1]);
        v = v > 0.f ? v : 0.f;
        bf16 bb = f2b(v);
        embB[(size_t)row * 512 + c] = bb;
        float vb = b2f(bb);
        s += vb * vb;
    }
    red[t] = s; __syncthreads();
    for (int st = 128; st > 0; st >>= 1) { if (t < st) red[t] += red[t + st]; __syncthreads(); }
    if (t == 0) nrm[row] = red[0];
}

// -------------------------------- distance + softmax + weighted sum -------
__global__ __launch_bounds__(256) void corr_kernel(const float* __restrict__ inner,
                                                   const float* __restrict__ nrm,
                                                   const float* __restrict__ tgt,
                                                   float* __restrict__ out) {
    __shared__ float red[256];
    int blk = blockIdx.x;                 // b*N + n
    int b = blk >> 11, n = blk & (NN - 1);
    int t = threadIdx.x;
    const float* inr = inner + ((size_t)b * NN + n) * NN;
    float xx = nrm[b * NN + n];
    float dloc[8];
    float vmax = -INFINITY;
#pragma unroll
    for (int i = 0; i < 8; ++i) {
        int m = t + i * 256;
        float pd = (xx - 2.f * inr[m]) + nrm[BNr + b * NN + m];
        float d = pd > 0.f ? sqrtf(pd) : 0.f;
        dloc[i] = d;
        vmax = fmaxf(vmax, -d);
    }
    red[t] = vmax; __syncthreads();
    for (int s = 128; s > 0; s >>= 1) { if (t < s) red[t] = fmaxf(red[t], red[t + s]); __syncthreads(); }
    vmax = red[0]; __syncthreads();
    const float* tp = tgt + (size_t)b * 3 * NN;
    float se = 0.f, s0 = 0.f, s1 = 0.f, s2 = 0.f;
#pragma unroll
    for (int i = 0; i < 8; ++i) {
        int m = t + i * 256;
        float p = expf(-dloc[i] - vmax);
        se += p;
        s0 += p * tp[m]; s1 += p * tp[NN + m]; s2 += p * tp[2 * NN + m];
    }
    red[t] = se; __syncthreads();
    for (int s = 128; s > 0; s >>= 1) { if (t < s) red[t] += red[t + s]; __syncthreads(); }
    float tot = red[0]; __syncthreads();
    red[t] = s0; __syncthreads();
    for (int s = 128; s > 0; s >>= 1) { if (t < s) red[t] += red[t + s]; __syncthreads(); }
    float o0v = red[0]; __syncthreads();
    red[t] = s1; __syncthreads();
    for (int s = 128; s > 0; s >>= 1) { if (t < s) red[t] += red[t + s]; __syncthreads(); }
    float o1v = red[0]; __syncthreads();
    red[t] = s2; __syncthreads();
    for (int s = 128; s > 0; s >>= 1) { if (t < s) red[t] += red[t + s]; __syncthreads(); }
    float o2v = red[0];
    if (t == 0) {
        out[(size_t)b * 3 * NN + n]          = o0v / tot;
        out[(size_t)b * 3 * NN + NN + n]     = o1v / tot;
        out[(size_t)b * 3 * NN + 2 * NN + n] = o2v / tot;
    }
}

// ------------------------------------------------------------- driver -----
extern "C" void kernel_launch(void* const* d_in, const int* in_sizes, int n_in,
                              void* d_out, int out_size, void* d_ws, size_t ws_size,
                              hipStream_t stream) {
    const float* src = (const float*)d_in[0];
    const float* tgt = (const float*)d_in[1];
    const float* w1  = (const float*)d_in[2];
    const float* w2  = (const float*)d_in[3];
    const float* w3  = (const float*)d_in[4];
    const float* w4  = (const float*)d_in[5];
    const float* w5  = (const float*)d_in[6];
    const float* g1  = (const float*)d_in[7];
    const float* g2  = (const float*)d_in[8];
    const float* g3  = (const float*)d_in[9];
    const float* g4  = (const float*)d_in[10];
    const float* g5  = (const float*)d_in[11];
    const float* b1  = (const float*)d_in[12];
    const float* b2  = (const float*)d_in[13];
    const float* b3  = (const float*)d_in[14];
    const float* b4  = (const float*)d_in[15];
    const float* b5  = (const float*)d_in[16];
    float* out = (float*)d_out;
    char* ws = (char*)d_ws;
    (void)in_sizes; (void)n_in;

    size_t off = 0;
    auto alloc = [&](size_t bytes) { size_t o = off; off = (off + bytes + 255) & ~(size_t)255; return o; };
    int*   idx    = (int*)(ws + alloc((size_t)SR * 4));                 // 2 MB
    bf16*  H2     = (bf16*)(ws + alloc((size_t)SR * 64 * 2));           // 64 MB (overlay inner f32)
    bf16*  cat    = (bf16*)(ws + alloc((size_t)GG * BNr * 512 * 2));    // 16 MB
    bf16*  embB   = (bf16*)(ws + alloc((size_t)GG * BNr * 512 * 2));    // 16 MB
    float* h5     = (float*)(ws + alloc((size_t)GG * BNr * 512 * 4));   // 33.5 MB
    float* m4h    = (float*)(ws + alloc((size_t)GG * BNr * 512 * 4));   // 33.5 MB (2 halves x 256)
    float* nrm    = (float*)(ws + alloc((size_t)GG * BNr * 4));
    float* sums   = (float*)(ws + alloc(2048 * 4));
    float* g1s    = (float*)(ws + alloc(64 * 4));
    float* g1part = (float*)(ws + alloc((size_t)GG * 2048 * 32 * 4));   // 512 KB
    float* prm    = (float*)(ws + alloc(5 * 2048 * 4));
    bf16*  w2b    = (bf16*)(ws + alloc(4096 * 2));
    bf16*  w3b    = (bf16*)(ws + alloc(8192 * 2));
    bf16*  w4b    = (bf16*)(ws + alloc(32768 * 2));
    bf16*  w5b    = (bf16*)(ws + alloc(262144 * 2));
    float* P1 = prm, *P2 = prm + 2048, *P3 = prm + 4096, *P4 = prm + 6144, *P5 = prm + 8192;
    float* inner = (float*)H2;   // overlay: SR*64*2 bytes == B*N*N*4 bytes exactly

    if (ws_size < off) {
        hipMemsetAsync(d_out, 0, (size_t)out_size * 4, stream);
        return;
    }

    zero_kernel<<<8, 256, 0, stream>>>(sums, 2048);   // first-call poison guard
    knn_kernel<<<GG * BB * NN / 4, 256, 0, stream>>>(src, tgt, idx, g1part);
    cvt_all_kernel<<<1024, 256, 0, stream>>>(w2, w3, w4, w5, w2b, w3b, w4b, w5b);

    // layer-1 BN params: reduce knn's Gram partials, then finalize
    reduce_g1_kernel<<<GG * 27, 256, 0, stream>>>(g1part, g1s);
    finalize_l1_kernel<<<1, 128, 0, stream>>>(g1s, w1, g1, b1, (float)SGr, P1);

    // apply pass: F1+x1, l2 -> raw h2pre (H2) + h2 stats
    l12_mfma<<<SR / 256, 256, 0, stream>>>(src, tgt, w1, w2b, idx, P1, H2, cat, sums);
    finalize_bn_kernel<<<1, 128, 0, stream>>>(sums, 64, g2, b2, (float)SGr, P2);

    // layer 3 stats (bn2-on-load of raw H2) + x2 -> cat
    mfma_gemm<1, 4, 1><<<dim3(SR / 512, 2, 1), 256, 0, stream>>>(
        H2, w3b, nullptr, nullptr, 64, 0, 0, 0, 0, SGr, nullptr, sums, P2, cat);
    finalize_bn_kernel<<<2, 128, 0, stream>>>(sums, 128, g3, b3, (float)SGr, P3);

    // layers 3+4 chain: SINGLE pass, 2 barriers/chunk (h4 stats + x3 + m4h)
    chain34_mfma<<<1024, 512, 134656, stream>>>(H2, w3b, w4b, P2, P3, cat, sums, m4h);
    finalize_bn_kernel<<<4, 128, 0, stream>>>(sums, 256, g4, b4, (float)SGr, P4);
    x4_finalize<<<GG * BNr, 256, 0, stream>>>(m4h, P4, cat);

    // layer 5: single GEMM pass (raw h5 f32 + stats), then fused finalize
    mfma_gemm<3, 1, 0><<<dim3(GG * BNr / 128, 8, 1), 256, 0, stream>>>(
        cat, w5b, h5, nullptr, 512, 512, 0, 0, 0, BNr, nullptr, sums, nullptr, nullptr);
    finalize_bn_kernel<<<8, 128, 0, stream>>>(sums, 512, g5, b5, (float)BNr, P5);
    emb_finalize<<<GG * BNr, 256, 0, stream>>>(h5, P5, embB, nrm);

    // inner products: per-batch embB_src x embB_tgt^T -> inner (overlay on H2)
    mfma_gemm<0, 1, 0><<<dim3(NN / 128, NN / 64, BB), 256, 0, stream>>>(
        embB, embB + (size_t)BNr * 512, inner, nullptr, 512, 2048,
        (long long)NN * 512, (long long)NN * 512, (long long)NN * NN,
        SGr, nullptr, nullptr, nullptr, nullptr);

    // distance + softmax + weighted sum of tgt points
    corr_kernel<<<BB * NN, 256, 0, stream>>>(inner, nrm, tgt, out);
}

// Round 22
// 587.844 us; speedup vs baseline: 1.0362x; 1.0047x over previous
//
#include <hip/hip_runtime.h>
#include <hip/hip_bf16.h>
#include <math.h>

#define BB 4
#define NN 2048
#define KK 32
#define GG 2
constexpr int BNr = BB * NN;       // 8192 point-rows per group
constexpr int SGr = BB * NN * KK;  // 262144 sample rows per group
constexpr int SR  = GG * SGr;      // 524288 total sample rows

typedef __hip_bfloat16 bf16;
typedef __attribute__((ext_vector_type(8))) short bf16x8;
typedef __attribute__((ext_vector_type(4))) short s16x4;
typedef __attribute__((ext_vector_type(4))) float f32x4;
__device__ __forceinline__ float b2f(bf16 v) { return __bfloat162float(v); }
__device__ __forceinline__ bf16  f2b(float v) { return __float2bfloat16(v); }
__device__ __forceinline__ short f2bs(float v) { bf16 b = f2b(v); return *(short*)&b; }
__device__ __forceinline__ float bs2f(short s) { bf16 b; *(short*)&b = s; return b2f(b); }

// XOR swizzles for LDS tiles (byte-offset based; row = stride 128B / 256B)
#define SWZ128(b) ((b) ^ ((((b) >> 7) & 7) << 4))
#define SWZ256(b) ((b) ^ ((((b) >> 8) & 7) << 4))

// ------------------------------------------------- kNN (wave-per-query) ---
// + fused layer-1 feature Gram -> per-block partials (no global atomics).
__global__ __launch_bounds__(256) void knn_kernel(const float* __restrict__ src,
                                                  const float* __restrict__ tgt,
                                                  int* __restrict__ idx_out,
                                                  float* __restrict__ g1part) {
    __shared__ float pts[3 * NN];   // 24 KB
    __shared__ float xxs[NN];       // 8 KB
    __shared__ int   sel[4][32];
    __shared__ float Gs[27];
    int blk = blockIdx.x;           // (g*B+b)*(NN/4) + chunk
    int gb = blk >> 9;              // / (NN/4)
    int chunk = blk & 511;
    int g = gb >> 2, b = gb & 3;
    const float* x = (g == 0 ? src : tgt) + (size_t)b * 3 * NN;
    int t = threadIdx.x;
    if (t < 27) Gs[t] = 0.f;
    for (int i = t; i < 3 * NN; i += 256) pts[i] = x[i];
    __syncthreads();
    for (int m = t; m < NN; m += 256) {
        float p0 = pts[m], p1 = pts[NN + m], p2 = pts[2 * NN + m];
        xxs[m] = p0 * p0 + p1 * p1 + p2 * p2;
    }
    __syncthreads();
    int w = t >> 6, l = t & 63;
    int n = chunk * 4 + w;
    float q0 = pts[n], q1 = pts[NN + n], q2 = pts[2 * NN + n];
    float xxn = xxs[n];
    float d2[32];
#pragma unroll
    for (int s = 0; s < 32; ++s) {
        int m = s * 64 + l;
        float dot = q0 * pts[m] + q1 * pts[NN + m] + q2 * pts[2 * NN + m];
        d2[s] = (xxn - 2.0f * dot) + xxs[m];
    }
    // cached group minima (4 groups x 8 slots)
    float gval[4]; int gslot[4];
#pragma unroll
    for (int G = 0; G < 4; ++G) {
        float v = d2[G * 8]; int sl = G * 8;
#pragma unroll
        for (int s = 1; s < 8; ++s)
            if (d2[G * 8 + s] < v) { v = d2[G * 8 + s]; sl = G * 8 + s; }
        gval[G] = v; gslot[G] = sl;
    }
    int* outp = idx_out + ((size_t)gb * NN + n) * KK;
    for (int k = 0; k < KK; ++k) {
        float bv = fminf(fminf(gval[0], gval[1]), fminf(gval[2], gval[3]));
        float gv = bv;
#pragma unroll
        for (int off = 1; off < 64; off <<= 1) gv = fminf(gv, __shfl_xor(gv, off));
        unsigned long long mask = __ballot(bv == gv);
        int winner = (int)__builtin_ctzll(mask);
        if (l == winner) {
            int grp = (gval[0] == gv) ? 0 : (gval[1] == gv) ? 1 : (gval[2] == gv) ? 2 : 3;
#pragma unroll
            for (int G = 0; G < 4; ++G)
                if (G == grp) {
                    int bs = gslot[G];
                    outp[k] = bs * 64 + l;
                    sel[w][k] = bs * 64 + l;
#pragma unroll
                    for (int s = 0; s < 8; ++s)
                        if (G * 8 + s == bs) d2[G * 8 + s] = INFINITY;
                    float v = d2[G * 8]; int sl = G * 8;
#pragma unroll
                    for (int s = 1; s < 8; ++s)
                        if (d2[G * 8 + s] < v) { v = d2[G * 8 + s]; sl = G * 8 + s; }
                    gval[G] = v; gslot[G] = sl;
                }
        }
    }
    __syncthreads();   // sel visible across lanes
    // feature Gram accumulation (layer-1 BN stats)
    float nx = 0.f, ny = 0.f, nz = 0.f;
    if (l < 32) {
        int m = sel[w][l];
        nx = pts[m]; ny = pts[NN + m]; nz = pts[2 * NN + m];
    }
    float v9[9] = {nx * nx, nx * ny, nx * nz, ny * ny, ny * nz, nz * nz, nx, ny, nz};
#pragma unroll
    for (int e = 0; e < 9; ++e) {
#pragma unroll
        for (int off = 1; off < 64; off <<= 1) v9[e] += __shfl_xor(v9[e], off);
    }
    if (l == 0) {
        float c3[3] = {q0, q1, q2};
#pragma unroll
        for (int e = 0; e < 6; ++e) atomicAdd(&Gs[e], v9[e]);
#pragma unroll
        for (int a = 0; a < 3; ++a)
#pragma unroll
            for (int bb = 0; bb < 3; ++bb)
                atomicAdd(&Gs[6 + a * 3 + bb], v9[6 + a] * c3[bb]);
        atomicAdd(&Gs[15], 32.f * q0 * q0);
        atomicAdd(&Gs[16], 32.f * q0 * q1);
        atomicAdd(&Gs[17], 32.f * q0 * q2);
        atomicAdd(&Gs[18], 32.f * q1 * q1);
        atomicAdd(&Gs[19], 32.f * q1 * q2);
        atomicAdd(&Gs[20], 32.f * q2 * q2);
        atomicAdd(&Gs[21], v9[6]);
        atomicAdd(&Gs[22], v9[7]);
        atomicAdd(&Gs[23], v9[8]);
        atomicAdd(&Gs[24], 32.f * q0);
        atomicAdd(&Gs[25], 32.f * q1);
        atomicAdd(&Gs[26], 32.f * q2);
    }
    __syncthreads();
    if (t < 27) g1part[(size_t)blk * 32 + t] = Gs[t];   // plain store, no atomics
}

// reduce per-block Gram partials: 54 blocks, one (g,e) each
__global__ __launch_bounds__(256) void reduce_g1_kernel(const float* __restrict__ part,
                                                        float* __restrict__ g1s) {
    __shared__ float red[256];
    int bx = blockIdx.x;
    int g = bx / 27, e = bx - g * 27;
    int t = threadIdx.x;
    float s = 0.f;
    for (int b = t; b < 2048; b += 256) s += part[((size_t)g * 2048 + b) * 32 + e];
    red[t] = s; __syncthreads();
    for (int st = 128; st > 0; st >>= 1) { if (t < st) red[t] += red[t + st]; __syncthreads(); }
    if (t == 0) g1s[g * 27 + e] = red[0];
}

// ---------------------------------------------------------------- misc ----
__global__ void zero_kernel(float* __restrict__ p, int n) {
    int i = blockIdx.x * 256 + threadIdx.x;
    if (i < n) p[i] = 0.f;
}

__global__ void cvt_all_kernel(const float* __restrict__ w2, const float* __restrict__ w3,
                               const float* __restrict__ w4, const float* __restrict__ w5,
                               bf16* __restrict__ w2b, bf16* __restrict__ w3b,
                               bf16* __restrict__ w4b, bf16* __restrict__ w5b) {
    int i = blockIdx.x * 256 + threadIdx.x;
    if (i < 4096)   w2b[i] = f2b(w2[i]);
    if (i < 8192)   w3b[i] = f2b(w3[i]);
    if (i < 32768)  w4b[i] = f2b(w4[i]);
    if (i < 262144) w5b[i] = f2b(w5[i]);
}

// finalize: compute scale/shift and zero the consumed sums for the next stage
__global__ void finalize_bn_kernel(float* __restrict__ sums, int C,
                                   const float* __restrict__ gamma,
                                   const float* __restrict__ beta,
                                   float cnt, float* __restrict__ params) {
    int i = blockIdx.x * blockDim.x + threadIdx.x;
    if (i >= GG * C) return;
    int g = i / C, c = i - g * C;
    float s  = sums[(g * 512 + c) * 2 + 0];
    float sq = sums[(g * 512 + c) * 2 + 1];
    float mean = s / cnt;
    float var = sq / cnt - mean * mean;
    if (var < 0.f) var = 0.f;
    float sc = gamma[c] * rsqrtf(var + 1e-5f);
    params[(g * 512 + c) * 2 + 0] = sc;
    params[(g * 512 + c) * 2 + 1] = beta[c] - mean * sc;
    sums[(g * 512 + c) * 2 + 0] = 0.f;
    sums[(g * 512 + c) * 2 + 1] = 0.f;
}

// layer-1 BN params from feature Gram: s = w.fsum, q = w^T G w
__global__ void finalize_l1_kernel(const float* __restrict__ g1s,
                                   const float* __restrict__ w1,
                                   const float* __restrict__ gamma,
                                   const float* __restrict__ beta,
                                   float cnt, float* __restrict__ params) {
    int i = blockIdx.x * blockDim.x + threadIdx.x;
    if (i >= GG * 64) return;
    int g = i >> 6, o = i & 63;
    const float* G = g1s + g * 27;
    float wv[6];
#pragma unroll
    for (int c = 0; c < 6; ++c) wv[c] = w1[o * 6 + c];
    float s = wv[0] * G[21] + wv[1] * G[22] + wv[2] * G[23] +
              wv[3] * G[24] + wv[4] * G[25] + wv[5] * G[26];
    const int UT[6][6] = {{0, 1, 2, 6, 7, 8},   {1, 3, 4, 9, 10, 11},
                          {2, 4, 5, 12, 13, 14},{6, 9, 12, 15, 16, 17},
                          {7, 10, 13, 16, 18, 19},{8, 11, 14, 17, 19, 20}};
    float q = 0.f;
#pragma unroll
    for (int a = 0; a < 6; ++a)
#pragma unroll
        for (int bb = 0; bb < 6; ++bb) q += wv[a] * wv[bb] * G[UT[a][bb]];
    float mean = s / cnt;
    float var = q / cnt - mean * mean;
    if (var < 0.f) var = 0.f;
    float sc = gamma[o] * rsqrtf(var + 1e-5f);
    params[(g * 512 + o) * 2 + 0] = sc;
    params[(g * 512 + o) * 2 + 1] = beta[o] - mean * sc;
}

// ----------------------------------------------- MFMA layers 1+2 ----------
// Apply pass only: gather -> l1 MFMA -> bn1+relu -> F1 (LDS) + x1 -> cat,
// l2 MFMA -> store RAW h2pre -> H2, accumulate h2pre stats -> sums.
__global__ __launch_bounds__(256, 3) void l12_mfma(
    const float* __restrict__ src, const float* __restrict__ tgt,
    const float* __restrict__ w1, const bf16* __restrict__ w2b,
    const int* __restrict__ idx, const float* __restrict__ p1,
    bf16* __restrict__ H2, bf16* __restrict__ cat, float* __restrict__ sums) {
    __shared__ char F1s[32768];    // [256][64] bf16 swz128
    __shared__ char W2s[8192];     // [64][64] bf16 swz128
    __shared__ float epiA[512];    // x1 int-max [8][64]
    __shared__ float epiB[128];    // h2 stats [64][2]
    int tid = threadIdx.x;
    int w = tid >> 6, l = tid & 63, lg = l >> 4, lr = l & 15;
    long long row0 = (long long)blockIdx.x * 256;
    int g = (int)(row0 / SGr);

    epiA[tid] = 0.f; epiA[tid + 256] = 0.f;
    if (tid < 128) epiB[tid] = 0.f;
    for (int s = tid; s < 512; s += 256)
        *(bf16x8*)(W2s + SWZ128(s * 16)) = *(const bf16x8*)(w2b + s * 8);

    bf16x8 af[4];
#pragma unroll
    for (int i = 0; i < 4; ++i) {
        af[i] = (bf16x8){0, 0, 0, 0, 0, 0, 0, 0};
        if (lg == 0) {
            int rr = (int)row0 + w * 64 + 16 * i + lr;
            int nrow = rr >> 5;
            int n = nrow & (NN - 1);
            int gb = nrow >> 11;
            int b = gb & 3, gg = gb >> 2;
            const float* x = (gg ? tgt : src) + (size_t)b * 3 * NN;
            int j = idx[rr];
            af[i][0] = f2bs(x[j]);
            af[i][1] = f2bs(x[NN + j]);
            af[i][2] = f2bs(x[2 * NN + j]);
            af[i][3] = f2bs(x[n]);
            af[i][4] = f2bs(x[NN + n]);
            af[i][5] = f2bs(x[2 * NN + n]);
        }
    }
    bf16x8 bf1[4];
#pragma unroll
    for (int j = 0; j < 4; ++j) {
        bf1[j] = (bf16x8){0, 0, 0, 0, 0, 0, 0, 0};
        if (lg == 0) {
            int o = 16 * j + lr;
#pragma unroll
            for (int c = 0; c < 6; ++c) bf1[j][c] = f2bs(w1[o * 6 + c]);
        }
    }

    f32x4 acc1[4][4] = {};
#pragma unroll
    for (int i = 0; i < 4; ++i)
#pragma unroll
        for (int j = 0; j < 4; ++j)
            acc1[i][j] = __builtin_amdgcn_mfma_f32_16x16x32_bf16(af[i], bf1[j], acc1[i][j], 0, 0, 0);

    __syncthreads();

    // bn1 + relu -> F1 (bf16) + x1 max
#pragma unroll
    for (int j = 0; j < 4; ++j) {
        int c = 16 * j + lr;
        float sc = p1[(g * 512 + c) * 2], sh = p1[(g * 512 + c) * 2 + 1];
#pragma unroll
        for (int i = 0; i < 4; ++i) {
            float m = 0.f;
#pragma unroll
            for (int r = 0; r < 4; ++r) {
                float v = fmaf(acc1[i][j][r], sc, sh);
                v = v > 0.f ? v : 0.f;
                m = fmaxf(m, v);
                int rowi = w * 64 + 16 * i + 4 * lg + r;
                *(bf16*)(F1s + SWZ128((rowi * 64 + c) * 2)) = f2b(v);
            }
            int p = 2 * w + (i >> 1);
            atomicMax((int*)epiA + p * 64 + c, __float_as_int(m));
        }
    }
    __syncthreads();

    {
        long long pt0 = row0 >> 5;
        for (int e = tid; e < 512; e += 256) {
            int p = e >> 6, c = e & 63;
            cat[(pt0 + p) * 512 + c] = f2b(__int_as_float(((int*)epiA)[p * 64 + c]));
        }
    }

    // layer 2 MFMA: F1 @ w2^T
    f32x4 acc2[4][4] = {};
#pragma unroll
    for (int ks = 0; ks < 2; ++ks) {
        bf16x8 bv[4];
#pragma unroll
        for (int j = 0; j < 4; ++j)
            bv[j] = *(bf16x8*)(W2s + SWZ128(((16 * j + lr) * 64 + ks * 32 + lg * 8) * 2));
#pragma unroll
        for (int i = 0; i < 4; ++i) {
            bf16x8 a = *(bf16x8*)(F1s + SWZ128(((w * 64 + 16 * i + lr) * 64 + ks * 32 + lg * 8) * 2));
#pragma unroll
            for (int j = 0; j < 4; ++j)
                acc2[i][j] = __builtin_amdgcn_mfma_f32_16x16x32_bf16(a, bv[j], acc2[i][j], 0, 0, 0);
        }
    }

    // store RAW h2pre + accumulate h2pre stats
#pragma unroll
    for (int j = 0; j < 4; ++j) {
        int c = 16 * j + lr;
        float s = 0.f, q = 0.f;
#pragma unroll
        for (int i = 0; i < 4; ++i)
#pragma unroll
            for (int r = 0; r < 4; ++r) {
                float v = acc2[i][j][r];
                s += v; q += v * v;
                long long gr = row0 + w * 64 + 16 * i + 4 * lg + r;
                H2[gr * 64 + c] = f2b(v);
            }
        s += __shfl_xor(s, 16); s += __shfl_xor(s, 32);
        q += __shfl_xor(q, 16); q += __shfl_xor(q, 32);
        if (lg == 0) {
            atomicAdd(&epiB[c * 2], s);
            atomicAdd(&epiB[c * 2 + 1], q);
        }
    }
    __syncthreads();
    if (tid < 128) atomicAdd(&sums[g * 1024 + tid], epiB[tid]);
}

// ------------------------------------------- MFMA chain: layers 3+4 -------
// SINGLE pass, 2 barriers/chunk + T14 prefetch: chunk+1's H2 loads issued
// after F3 writes (latency hides under l4+epilogue); bn2+ds_write placed
// after the epilogue (A2s free -- last read was l3, done before F3 barrier).
// h4pre stats + x3 (scalar F3 re-read) + per-wave x4 half-max direct to
// global m4h (max commutes with relu(bn4), gamma4 > 0).
__global__ __launch_bounds__(512, 2) void chain34_mfma(
    const bf16* __restrict__ H2, const bf16* __restrict__ w3b,
    const bf16* __restrict__ w4b, const float* __restrict__ p2,
    const float* __restrict__ p3, bf16* __restrict__ cat,
    float* __restrict__ sums, float* __restrict__ m4h) {
    extern __shared__ char smem[];
    char* W3s = smem;                       // 16384  [128][64] bf16 swz128
    char* W4s = smem + 16384;               // 65536  [256][128] bf16 swz256
    char* A2s = smem + 81920;               // 16384  [128][64] bf16 swz128
    char* F3s = smem + 98304;               // 32768  [128][128] bf16 swz256
    float* P3s  = (float*)(smem + 131072);  // 1024 B (256 f32)
    float* epiS = (float*)(smem + 132096);  // 2048 B (512 f32) h4 stats
    float* P2s  = (float*)(smem + 134144);  // 512 B (128 f32)

    int tid = threadIdx.x;
    int w = tid >> 6, l = tid & 63, lg = l >> 4, lr = l & 15;
    long long rowB0 = (long long)blockIdx.x * 512;
    int g = (int)(rowB0 / SGr);

    for (int s = tid; s < 1024; s += 512)
        *(bf16x8*)(W3s + SWZ128(s * 16)) = *(const bf16x8*)(w3b + s * 8);
    for (int s = tid; s < 4096; s += 512)
        *(bf16x8*)(W4s + SWZ256(s * 16)) = *(const bf16x8*)(w4b + s * 8);
    if (tid < 256) P3s[tid] = p3[g * 1024 + tid];
    if (tid < 128) P2s[tid] = p2[g * 1024 + tid];
    epiS[tid & 511] = 0.f;

    // prologue: issue chunk-0 loads (overlap with weight staging)
    bf16x8 rv0 = *(const bf16x8*)(H2 + rowB0 * 64 + (long long)tid * 8);
    bf16x8 rv1 = *(const bf16x8*)(H2 + rowB0 * 64 + (long long)(tid + 512) * 8);
    __syncthreads();   // weights + params staged

    // bn3 params for this lane's 4 channels (c = 16w + 4lg + r)
    float sc3[4], sh3[4];
#pragma unroll
    for (int r = 0; r < 4; ++r) {
        int c = 16 * w + 4 * lg + r;
        sc3[r] = P3s[c * 2]; sh3[r] = P3s[c * 2 + 1];
    }

    // bn2 + swizzled A2 write
    auto bn2w = [&](bf16x8 rv, int s) {
        int cb = (s & 7) * 8;
        bf16x8 ov;
#pragma unroll
        for (int e = 0; e < 8; ++e) {
            float v = fmaf(bs2f(rv[e]), P2s[(cb + e) * 2], P2s[(cb + e) * 2 + 1]);
            v = v > 0.f ? v : 0.f;
            ov[e] = f2bs(v);
        }
        *(bf16x8*)(A2s + SWZ128(s * 16)) = ov;
    };
    bn2w(rv0, tid); bn2w(rv1, tid + 512);
    __syncthreads();   // A2 chunk 0 ready

    for (int chunk = 0; chunk < 4; ++chunk) {
        long long row0 = rowB0 + chunk * 128;
        // layer 3 (swapped operands): wave owns channels 16w..16w+15
        {
            f32x4 acc3[8] = {};
#pragma unroll
            for (int ks = 0; ks < 2; ++ks) {
                bf16x8 wf = *(bf16x8*)(W3s + SWZ128(((16 * w + lr) * 64 + ks * 32 + lg * 8) * 2));
#pragma unroll
                for (int j = 0; j < 8; ++j) {
                    bf16x8 a2 = *(bf16x8*)(A2s + SWZ128(((16 * j + lr) * 64 + ks * 32 + lg * 8) * 2));
                    acc3[j] = __builtin_amdgcn_mfma_f32_16x16x32_bf16(wf, a2, acc3[j], 0, 0, 0);
                }
            }
            // bn3+relu -> F3: packed 4-channel b64 write per j (row = 16j+lr)
#pragma unroll
            for (int j = 0; j < 8; ++j) {
                s16x4 pk;
#pragma unroll
                for (int r = 0; r < 4; ++r) {
                    float v = fmaf(acc3[j][r], sc3[r], sh3[r]);
                    v = v > 0.f ? v : 0.f;
                    pk[r] = f2bs(v);
                }
                *(s16x4*)(F3s + SWZ256(((16 * j + lr) * 128 + 16 * w + 4 * lg) * 2)) = pk;
            }
        }
        // T14: issue next chunk's H2 loads (hide under l4 + epilogue)
        if (chunk < 3) {
            long long rn = rowB0 + (chunk + 1) * 128;
            rv0 = *(const bf16x8*)(H2 + rn * 64 + (long long)tid * 8);
            rv1 = *(const bf16x8*)(H2 + rn * 64 + (long long)(tid + 512) * 8);
        }
        __syncthreads();   // F3 ready; all A2s reads (l3) complete

        // layer 4: rows 16w..16w+15 per wave; B-frags from LDS W4s
        f32x4 acc4[16] = {};
#pragma unroll
        for (int ks = 0; ks < 4; ++ks) {
            bf16x8 a = *(bf16x8*)(F3s + SWZ256(((16 * w + lr) * 128 + ks * 32 + lg * 8) * 2));
#pragma unroll
            for (int j = 0; j < 16; ++j) {
                bf16x8 b = *(bf16x8*)(W4s + SWZ256(((16 * j + lr) * 128 + ks * 32 + lg * 8) * 2));
                acc4[j] = __builtin_amdgcn_mfma_f32_16x16x32_bf16(a, b, acc4[j], 0, 0, 0);
            }
        }

        // h4pre stats + per-wave half-max DIRECT to global (unique writer)
        {
            long long pt = (row0 >> 5) + (w >> 1);   // point owned by this wave pair
#pragma unroll
            for (int j = 0; j < 16; ++j) {
                int c = 16 * j + lr;
                float s = acc4[j][0] + acc4[j][1] + acc4[j][2] + acc4[j][3];
                float q = acc4[j][0] * acc4[j][0] + acc4[j][1] * acc4[j][1] +
                          acc4[j][2] * acc4[j][2] + acc4[j][3] * acc4[j][3];
                float m = fmaxf(fmaxf(acc4[j][0], acc4[j][1]), fmaxf(acc4[j][2], acc4[j][3]));
                s += __shfl_xor(s, 16); s += __shfl_xor(s, 32);
                q += __shfl_xor(q, 16); q += __shfl_xor(q, 32);
                m = fmaxf(m, __shfl_xor(m, 16));
                m = fmaxf(m, __shfl_xor(m, 32));
                if (lg == 0) {
                    atomicAdd(&epiS[c * 2], s);
                    atomicAdd(&epiS[c * 2 + 1], q);
                    m4h[(pt * 2 + (w & 1)) * 256 + c] = m;   // plain global store
                }
            }
        }
        // x3 from F3 (post-relu bf16)
        {
            long long pt0 = row0 >> 5;
            int p = tid >> 7, c = tid & 127;
            float m = 0.f;
            for (int r = 0; r < 32; ++r)
                m = fmaxf(m, b2f(*(bf16*)(F3s + SWZ256(((p * 32 + r) * 128 + c) * 2))));
            cat[(pt0 + p) * 512 + 128 + c] = f2b(m);
        }
        // write next chunk's A2 (A2s free: last reader was l3 this chunk)
        if (chunk < 3) {
            bn2w(rv0, tid); bn2w(rv1, tid + 512);
            __syncthreads();   // A2 ready; x3's F3 reads done before next F3 writes
        }
    }
    __syncthreads();
    atomicAdd(&sums[g * 1024 + (tid & 511)], tid < 512 ? epiS[tid] : 0.f);
}

// ------------- x4 finalize: relu(bn4(max of 2 halves)) -> cat[256..512] ---
__global__ __launch_bounds__(256) void x4_finalize(const float* __restrict__ m4h,
                                                   const float* __restrict__ p4,
                                                   bf16* __restrict__ cat) {
    int row = blockIdx.x;          // g*BNr + pt
    int c = threadIdx.x;
    int g = row / BNr;
    float m = fmaxf(m4h[((size_t)row * 2) * 256 + c], m4h[((size_t)row * 2 + 1) * 256 + c]);
    float v = fmaf(m, p4[(g * 512 + c) * 2], p4[(g * 512 + c) * 2 + 1]);
    v = v > 0.f ? v : 0.f;
    cat[(size_t)row * 512 + 256 + c] = f2b(v);
}

// ----------------------------------------------------- generic MFMA GEMM --
// BNA=1: bn(pba)+relu on A during staging + x2 maxes -> cat (blockIdx.y==0).
// MODE 0: store f32. MODE 1: stats only. MODE 3: store f32 AND stats.
template <int MODE, int CH, int BNA>
__global__ __launch_bounds__(256, 4) void mfma_gemm(
    const bf16* __restrict__ A, const bf16* __restrict__ Wt,
    float* __restrict__ OutF, bf16* __restrict__ OutB,
    int Cin, int ldOut, long long sA, long long sW, long long sO,
    int rowsPerGroup, const float* __restrict__ params, float* __restrict__ sums,
    const float* __restrict__ pba, bf16* __restrict__ cat) {
    __shared__ char As[16384];   // [128][64] bf16 swz128
    __shared__ char Bs[8192];    // [64][64] bf16 swz128
    __shared__ float epi[128];
    __shared__ float PBs[128];
    __shared__ int x2m[256];     // [4 pts][64 ch]
    int tid = threadIdx.x;
    int w = tid >> 6, l = tid & 63, lg = l >> 4, lr = l & 15;
    int bz = blockIdx.z;
    const bf16* Ap = A + (long long)bz * sA;
    const bf16* Wp = Wt + (long long)bz * sW;
    int o0 = blockIdx.y * 64;
    long long rowB0 = (long long)blockIdx.x * (128 * CH);
    int g = (int)(rowB0 / rowsPerGroup);
    if ((MODE == 1 || MODE == 3) && tid < 128) epi[tid] = 0.f;
    if (BNA && tid < 128) PBs[tid] = pba[g * 1024 + tid];
    int wr = (w >> 1) * 64, wc = (w & 1) * 32;

    for (int ch = 0; ch < CH; ++ch) {
        long long row0 = rowB0 + (long long)ch * 128;
        if (BNA) {
            __syncthreads();
            if (tid < 256) x2m[tid] = 0;
        }
        f32x4 acc[4][2] = {};
        for (int k0 = 0; k0 < Cin; k0 += 64) {
            __syncthreads();
            for (int s = tid; s < 1024; s += 256) {
                if (BNA) {
                    bf16x8 rv = *(const bf16x8*)(Ap + (row0 + (s >> 3)) * Cin + k0 + (s & 7) * 8);
                    int cb = k0 + (s & 7) * 8;
                    int pt = (s >> 3) >> 5;
                    bf16x8 ov;
#pragma unroll
                    for (int e = 0; e < 8; ++e) {
                        float v = fmaf(bs2f(rv[e]), PBs[(cb + e) * 2], PBs[(cb + e) * 2 + 1]);
                        v = v > 0.f ? v : 0.f;
                        ov[e] = f2bs(v);
                        atomicMax(&x2m[pt * 64 + cb + e], __float_as_int(v));
                    }
                    *(bf16x8*)(As + SWZ128(s * 16)) = ov;
                } else {
                    *(bf16x8*)(As + SWZ128(s * 16)) =
                        *(const bf16x8*)(Ap + (row0 + (s >> 3)) * Cin + k0 + (s & 7) * 8);
                }
            }
            for (int s = tid; s < 512; s += 256)
                *(bf16x8*)(Bs + SWZ128(s * 16)) =
                    *(const bf16x8*)(Wp + (long long)(o0 + (s >> 3)) * Cin + k0 + (s & 7) * 8);
            __syncthreads();
#pragma unroll
            for (int ks = 0; ks < 2; ++ks) {
                bf16x8 b0 = *(bf16x8*)(Bs + SWZ128(((wc + lr) * 64 + ks * 32 + lg * 8) * 2));
                bf16x8 b1 = *(bf16x8*)(Bs + SWZ128(((wc + 16 + lr) * 64 + ks * 32 + lg * 8) * 2));
#pragma unroll
                for (int i = 0; i < 4; ++i) {
                    bf16x8 a = *(bf16x8*)(As + SWZ128(((wr + 16 * i + lr) * 64 + ks * 32 + lg * 8) * 2));
                    acc[i][0] = __builtin_amdgcn_mfma_f32_16x16x32_bf16(a, b0, acc[i][0], 0, 0, 0);
                    acc[i][1] = __builtin_amdgcn_mfma_f32_16x16x32_bf16(a, b1, acc[i][1], 0, 0, 0);
                }
            }
        }
        if (BNA && blockIdx.y == 0) {
            long long pt0 = row0 >> 5;
            if (tid < 256) {
                int p = tid >> 6, c = tid & 63;
                cat[(pt0 + p) * 512 + 64 + c] = f2b(__int_as_float(x2m[tid]));
            }
        }
        if (MODE == 1 || MODE == 3) {
#pragma unroll
            for (int j = 0; j < 2; ++j) {
                int c = wc + 16 * j + lr;
                float s = 0.f, q = 0.f;
#pragma unroll
                for (int i = 0; i < 4; ++i)
#pragma unroll
                    for (int r = 0; r < 4; ++r) {
                        float v = acc[i][j][r];
                        s += v; q += v * v;
                    }
                s += __shfl_xor(s, 16); s += __shfl_xor(s, 32);
                q += __shfl_xor(q, 16); q += __shfl_xor(q, 32);
                if (lg == 0) {
                    atomicAdd(&epi[c * 2], s);
                    atomicAdd(&epi[c * 2 + 1], q);
                }
            }
        }
        if (MODE == 0 || MODE == 3) {
            float* Op = OutF + (long long)bz * sO;
#pragma unroll
            for (int j = 0; j < 2; ++j) {
                int gc = o0 + wc + 16 * j + lr;
#pragma unroll
                for (int i = 0; i < 4; ++i)
#pragma unroll
                    for (int r = 0; r < 4; ++r) {
                        long long gr = row0 + wr + 16 * i + 4 * lg + r;
                        Op[gr * ldOut + gc] = acc[i][j][r];
                    }
            }
        }
    }
    if (MODE == 1 || MODE == 3) {
        __syncthreads();
        if (tid < 128) atomicAdd(&sums[g * 1024 + o0 * 2 + tid], epi[tid]);
    }
}

// --------------------------------- l5 finalize: bn+relu -> embB + norms ---
__global__ __launch_bounds__(256) void emb_finalize(const float* __restrict__ h5,
                                                    const float* __restrict__ p5,
                                                    bf16* __restrict__ embB,
                                                    float* __restrict__ nrm) {
    __shared__ float red[256];
    int row = blockIdx.x; int t = threadIdx.x;
    int g = row / BNr;
    float s = 0.f;
#pragma unroll
    for (int i = 0; i < 2; ++i) {
        int c = t + i * 256;
        float v = fmaf(h5[(size_t)row * 512 + c], p5[(g * 512 + c) * 2], p5[(g * 512 + c) * 2 + 1]);
        v = v > 0.f ? v : 0.f;
        bf16 bb = f2b(v);
        embB[(size_t)row * 512 + c] = bb;
        float vb = b2f(bb);
        s += vb * vb;
    }
    red[t] = s; __syncthreads();
    for (int st = 128; st > 0; st >>= 1) { if (t < st) red[t] += red[t + st]; __syncthreads(); }
    if (t == 0) nrm[row] = red[0];
}

// -------------------------------- distance + softmax + weighted sum -------
__global__ __launch_bounds__(256) void corr_kernel(const float* __restrict__ inner,
                                                   const float* __restrict__ nrm,
                                                   const float* __restrict__ tgt,
                                                   float* __restrict__ out) {
    __shared__ float red[256];
    int blk = blockIdx.x;                 // b*N + n
    int b = blk >> 11, n = blk & (NN - 1);
    int t = threadIdx.x;
    const float* inr = inner + ((size_t)b * NN + n) * NN;
    float xx = nrm[b * NN + n];
    float dloc[8];
    float vmax = -INFINITY;
#pragma unroll
    for (int i = 0; i < 8; ++i) {
        int m = t + i * 256;
        float pd = (xx - 2.f * inr[m]) + nrm[BNr + b * NN + m];
        float d = pd > 0.f ? sqrtf(pd) : 0.f;
        dloc[i] = d;
        vmax = fmaxf(vmax, -d);
    }
    red[t] = vmax; __syncthreads();
    for (int s = 128; s > 0; s >>= 1) { if (t < s) red[t] = fmaxf(red[t], red[t + s]); __syncthreads(); }
    vmax = red[0]; __syncthreads();
    const float* tp = tgt + (size_t)b * 3 * NN;
    float se = 0.f, s0 = 0.f, s1 = 0.f, s2 = 0.f;
#pragma unroll
    for (int i = 0; i < 8; ++i) {
        int m = t + i * 256;
        float p = expf(-dloc[i] - vmax);
        se += p;
        s0 += p * tp[m]; s1 += p * tp[NN + m]; s2 += p * tp[2 * NN + m];
    }
    red[t] = se; __syncthreads();
    for (int s = 128; s > 0; s >>= 1) { if (t < s) red[t] += red[t + s]; __syncthreads(); }
    float tot = red[0]; __syncthreads();
    red[t] = s0; __syncthreads();
    for (int s = 128; s > 0; s >>= 1) { if (t < s) red[t] += red[t + s]; __syncthreads(); }
    float o0v = red[0]; __syncthreads();
    red[t] = s1; __syncthreads();
    for (int s = 128; s > 0; s >>= 1) { if (t < s) red[t] += red[t + s]; __syncthreads(); }
    float o1v = red[0]; __syncthreads();
    red[t] = s2; __syncthreads();
    for (int s = 128; s > 0; s >>= 1) { if (t < s) red[t] += red[t + s]; __syncthreads(); }
    float o2v = red[0];
    if (t == 0) {
        out[(size_t)b * 3 * NN + n]          = o0v / tot;
        out[(size_t)b * 3 * NN + NN + n]     = o1v / tot;
        out[(size_t)b * 3 * NN + 2 * NN + n] = o2v / tot;
    }
}

// ------------------------------------------------------------- driver -----
extern "C" void kernel_launch(void* const* d_in, const int* in_sizes, int n_in,
                              void* d_out, int out_size, void* d_ws, size_t ws_size,
                              hipStream_t stream) {
    const float* src = (const float*)d_in[0];
    const float* tgt = (const float*)d_in[1];
    const float* w1  = (const float*)d_in[2];
    const float* w2  = (const float*)d_in[3];
    const float* w3  = (const float*)d_in[4];
    const float* w4  = (const float*)d_in[5];
    const float* w5  = (const float*)d_in[6];
    const float* g1  = (const float*)d_in[7];
    const float* g2  = (const float*)d_in[8];
    const float* g3  = (const float*)d_in[9];
    const float* g4  = (const float*)d_in[10];
    const float* g5  = (const float*)d_in[11];
    const float* b1  = (const float*)d_in[12];
    const float* b2  = (const float*)d_in[13];
    const float* b3  = (const float*)d_in[14];
    const float* b4  = (const float*)d_in[15];
    const float* b5  = (const float*)d_in[16];
    float* out = (float*)d_out;
    char* ws = (char*)d_ws;
    (void)in_sizes; (void)n_in;

    size_t off = 0;
    auto alloc = [&](size_t bytes) { size_t o = off; off = (off + bytes + 255) & ~(size_t)255; return o; };
    int*   idx    = (int*)(ws + alloc((size_t)SR * 4));                 // 2 MB
    bf16*  H2     = (bf16*)(ws + alloc((size_t)SR * 64 * 2));           // 64 MB (overlay inner f32)
    bf16*  cat    = (bf16*)(ws + alloc((size_t)GG * BNr * 512 * 2));    // 16 MB
    bf16*  embB   = (bf16*)(ws + alloc((size_t)GG * BNr * 512 * 2));    // 16 MB
    float* h5     = (float*)(ws + alloc((size_t)GG * BNr * 512 * 4));   // 33.5 MB
    float* m4h    = (float*)(ws + alloc((size_t)GG * BNr * 512 * 4));   // 33.5 MB (2 halves x 256)
    float* nrm    = (float*)(ws + alloc((size_t)GG * BNr * 4));
    float* sums   = (float*)(ws + alloc(2048 * 4));
    float* g1s    = (float*)(ws + alloc(64 * 4));
    float* g1part = (float*)(ws + alloc((size_t)GG * 2048 * 32 * 4));   // 512 KB
    float* prm    = (float*)(ws + alloc(5 * 2048 * 4));
    bf16*  w2b    = (bf16*)(ws + alloc(4096 * 2));
    bf16*  w3b    = (bf16*)(ws + alloc(8192 * 2));
    bf16*  w4b    = (bf16*)(ws + alloc(32768 * 2));
    bf16*  w5b    = (bf16*)(ws + alloc(262144 * 2));
    float* P1 = prm, *P2 = prm + 2048, *P3 = prm + 4096, *P4 = prm + 6144, *P5 = prm + 8192;
    float* inner = (float*)H2;   // overlay: SR*64*2 bytes == B*N*N*4 bytes exactly

    if (ws_size < off) {
        hipMemsetAsync(d_out, 0, (size_t)out_size * 4, stream);
        return;
    }

    zero_kernel<<<8, 256, 0, stream>>>(sums, 2048);   // first-call poison guard
    knn_kernel<<<GG * BB * NN / 4, 256, 0, stream>>>(src, tgt, idx, g1part);
    cvt_all_kernel<<<1024, 256, 0, stream>>>(w2, w3, w4, w5, w2b, w3b, w4b, w5b);

    // layer-1 BN params: reduce knn's Gram partials, then finalize
    reduce_g1_kernel<<<GG * 27, 256, 0, stream>>>(g1part, g1s);
    finalize_l1_kernel<<<1, 128, 0, stream>>>(g1s, w1, g1, b1, (float)SGr, P1);

    // apply pass: F1+x1, l2 -> raw h2pre (H2) + h2 stats
    l12_mfma<<<SR / 256, 256, 0, stream>>>(src, tgt, w1, w2b, idx, P1, H2, cat, sums);
    finalize_bn_kernel<<<1, 128, 0, stream>>>(sums, 64, g2, b2, (float)SGr, P2);

    // layer 3 stats (bn2-on-load of raw H2) + x2 -> cat
    mfma_gemm<1, 4, 1><<<dim3(SR / 512, 2, 1), 256, 0, stream>>>(
        H2, w3b, nullptr, nullptr, 64, 0, 0, 0, 0, SGr, nullptr, sums, P2, cat);
    finalize_bn_kernel<<<2, 128, 0, stream>>>(sums, 128, g3, b3, (float)SGr, P3);

    // layers 3+4 chain: SINGLE pass, prefetched, 2 barriers/chunk
    chain34_mfma<<<1024, 512, 134656, stream>>>(H2, w3b, w4b, P2, P3, cat, sums, m4h);
    finalize_bn_kernel<<<4, 128, 0, stream>>>(sums, 256, g4, b4, (float)SGr, P4);
    x4_finalize<<<GG * BNr, 256, 0, stream>>>(m4h, P4, cat);

    // layer 5: single GEMM pass (raw h5 f32 + stats), then fused finalize
    mfma_gemm<3, 1, 0><<<dim3(GG * BNr / 128, 8, 1), 256, 0, stream>>>(
        cat, w5b, h5, nullptr, 512, 512, 0, 0, 0, BNr, nullptr, sums, nullptr, nullptr);
    finalize_bn_kernel<<<8, 128, 0, stream>>>(sums, 512, g5, b5, (float)BNr, P5);
    emb_finalize<<<GG * BNr, 256, 0, stream>>>(h5, P5, embB, nrm);

    // inner products: per-batch embB_src x embB_tgt^T -> inner (overlay on H2)
    mfma_gemm<0, 1, 0><<<dim3(NN / 128, NN / 64, BB), 256, 0, stream>>>(
        embB, embB + (size_t)BNr * 512, inner, nullptr, 512, 2048,
        (long long)NN * 512, (long long)NN * 512, (long long)NN * NN,
        SGr, nullptr, nullptr, nullptr, nullptr);

    // distance + softmax + weighted sum of tgt points
    corr_kernel<<<BB * NN, 256, 0, stream>>>(inner, nrm, tgt, out);
}